// Round 9
// baseline (607.924 us; speedup 1.0000x reference)
//
#include <hip/hip_runtime.h>
#include <math.h>
#include <float.h>

// Round 9: k_gemB/k_gemC rebuilt as register-blocked tiled GEMMs
// (64x64 tile, K-chunk 32 in LDS, 4x4 micro-tile/thread, vector loads).
// Fixes 7%-occupancy + scalar-load serialization seen in round-8 profile.
// All other kernels and the scratch map identical to green round 8.

#define APN 105
#define UEN 4000
#define H   128
#define H2  256
#define SS  10
#define INV_NEIGH (1.0f/11.0f)

__device__ __forceinline__ float frelu(float v){ return v > 0.f ? v : 0.f; }

// ---------------- two-hop indices ----------------
__global__ void k_twohop(const int* __restrict__ adj_ue, const int* __restrict__ adj_ap,
                         int* __restrict__ ap2ap, int* __restrict__ ue2ue){
  int idx = blockIdx.x*256 + threadIdx.x;
  if (idx >= (APN+UEN)*SS) return;
  if (idx < APN*SS){
    int s = idx % SS;
    ap2ap[idx] = adj_ue[adj_ap[idx]*SS + s];
  } else {
    int j = idx - APN*SS;
    int s = j % SS;
    ue2ue[j] = adj_ap[adj_ue[j]*SS + s];
  }
}

// ---------------- Family A: 4 slices x 4 K-splits over K=4000, n<APN ----------------
__global__ __launch_bounds__(128) void k_gemA4(
    const float* __restrict__ pl, const float* __restrict__ W1ap1,
    const float* __restrict__ W1ap2, const float* __restrict__ W1ue1,
    float* __restrict__ partial)
{
  __shared__ float plrow[1000];
  int n = blockIdx.x, slice = blockIdx.y, ks = blockIdx.z, t = threadIdx.x;
  int k0 = ks*1000;
  for (int j=t; j<1000; j+=128) plrow[j] = pl[(size_t)n*UEN + k0 + j];
  __syncthreads();
  const float* w; int lda;
  if      (slice == 0){ w = W1ap1;       lda = UEN+APN; }
  else if (slice == 1){ w = W1ap2;       lda = 2*UEN;   }
  else if (slice == 2){ w = W1ap2 + UEN; lda = 2*UEN;   }
  else                { w = W1ue1 + APN; lda = UEN+APN; }
  const float* wr = w + (size_t)t*lda + k0;
  float s0=0.f,s1=0.f,s2=0.f,s3=0.f;
  for (int j=0;j<1000;j+=4){
    s0 = fmaf(wr[j  ], plrow[j  ], s0);
    s1 = fmaf(wr[j+1], plrow[j+1], s1);
    s2 = fmaf(wr[j+2], plrow[j+2], s2);
    s3 = fmaf(wr[j+3], plrow[j+3], s3);
  }
  partial[((size_t)(slice*4+ks)*APN + n)*H + t] = (s0+s1)+(s2+s3);
}

__global__ __launch_bounds__(256) void k_redA(const float* __restrict__ partial,
                                              float* __restrict__ RA){
  int idx = blockIdx.x*256 + threadIdx.x;
  if (idx >= 4*APN*H) return;
  int slice = idx / (APN*H), r = idx % (APN*H);
  float s = 0.f;
  #pragma unroll
  for (int ks=0;ks<4;ks++) s += partial[((size_t)(slice*4+ks)*APN*H) + r];
  RA[idx] = s;
}

// ---------------- tiled GEMM inner core: 32-k chunk, 4x4 micro-tile ----------------
// As[k][m] (m = h), Bs[k][n] (n = u); acc[i][j] += As[k][ty*4+i]*Bs[k][tx*4+j]
__device__ __forceinline__ void tile_core(const float (*As)[68], const float (*Bs)[68],
                                          int tx, int ty, float acc[4][4])
{
  #pragma unroll
  for (int k=0;k<32;k++){
    float4 a = *(const float4*)&As[k][ty*4];
    float4 b = *(const float4*)&Bs[k][tx*4];
    acc[0][0]=fmaf(a.x,b.x,acc[0][0]); acc[0][1]=fmaf(a.x,b.y,acc[0][1]);
    acc[0][2]=fmaf(a.x,b.z,acc[0][2]); acc[0][3]=fmaf(a.x,b.w,acc[0][3]);
    acc[1][0]=fmaf(a.y,b.x,acc[1][0]); acc[1][1]=fmaf(a.y,b.y,acc[1][1]);
    acc[1][2]=fmaf(a.y,b.z,acc[1][2]); acc[1][3]=fmaf(a.y,b.w,acc[1][3]);
    acc[2][0]=fmaf(a.z,b.x,acc[2][0]); acc[2][1]=fmaf(a.z,b.y,acc[2][1]);
    acc[2][2]=fmaf(a.z,b.z,acc[2][2]); acc[2][3]=fmaf(a.z,b.w,acc[2][3]);
    acc[3][0]=fmaf(a.w,b.x,acc[3][0]); acc[3][1]=fmaf(a.w,b.y,acc[3][1]);
    acc[3][2]=fmaf(a.w,b.z,acc[3][2]); acc[3][3]=fmaf(a.w,b.w,acc[3][3]);
  }
}

// ---------------- Family B tiled: K=105 (padded 128), 4 slices, grid (63, 8) ----------------
// y: z = y>>1 (slice), h0 = (y&1)*64.
// z0 T3 = W1ue1[:, :105]   z1 T4 = W1ue2[:, :105]
// z2 U1 = W1ap1[:, 4000:]  z3 R4 = W1ue2[:, 105:]
__global__ __launch_bounds__(256) void k_gemB2(
    const float* __restrict__ pl, const float* __restrict__ W1ap1,
    const float* __restrict__ W1ue1, const float* __restrict__ W1ue2,
    float* __restrict__ T3, float* __restrict__ T4,
    float* __restrict__ U1, float* __restrict__ R4)
{
  __shared__ float As[32][68], Bs[32][68];
  int t = threadIdx.x, u0 = blockIdx.x*64, y = blockIdx.y;
  int z = y>>1, h0 = (y&1)*64;
  const float* w; int lda; float* op;
  if      (z == 0){ w = W1ue1;       lda = UEN+APN; op = T3; }
  else if (z == 1){ w = W1ue2;       lda = 2*APN;   op = T4; }
  else if (z == 2){ w = W1ap1 + UEN; lda = UEN+APN; op = U1; }
  else            { w = W1ue2 + APN; lda = 2*APN;   op = R4; }
  int tx = t&15, ty = t>>4;
  int hr = t>>2,  c0 = (t&3)*8;    // W staging: 64 rows x 4 thr, 8 k each
  int kr = t>>3, uu0 = (t&7)*8;    // X staging: 32 k-rows x 8 thr, 8 u each
  float acc[4][4] = {};
  for (int kc=0; kc<128; kc+=32){
    float w8[8], x8[8];
    const float* wr = w + (size_t)(h0+hr)*lda + kc + c0;
    #pragma unroll
    for (int i=0;i<8;i++) w8[i] = (kc+c0+i < APN) ? wr[i] : 0.f;
    const float* xr = pl + (size_t)(kc+kr)*UEN + u0 + uu0;
    #pragma unroll
    for (int i=0;i<8;i++)
      x8[i] = (kc+kr < APN && u0+uu0+i < UEN) ? xr[i] : 0.f;
    __syncthreads();
    #pragma unroll
    for (int i=0;i<8;i++) As[c0+i][hr] = w8[i];
    #pragma unroll
    for (int i=0;i<8;i++) Bs[kr][uu0+i] = x8[i];
    __syncthreads();
    tile_core(As, Bs, tx, ty, acc);
  }
  #pragma unroll
  for (int j=0;j<4;j++){
    int u = u0 + tx*4 + j;
    if (u < UEN){
      #pragma unroll
      for (int i=0;i<4;i++) op[(size_t)u*H + h0 + ty*4 + i] = acc[i][j];
    }
  }
}

// ---------------- Family C tiled: K=256, grid (63, 6) ----------------
// y: z = y>>1, h0 = (y&1)*64.
// z0 Ya7 = W2ue1[:, :256] -> X2ue[u][h]    z1 Ya8 = W2ue2[:, :256] -> X2ue[u][128+h]
// z2 Yb8 = W2ue2[:, 256:] -> Yb8[u][h]
__global__ __launch_bounds__(256) void k_gemC2(
    const float* __restrict__ Xue, const float* __restrict__ W2ue1,
    const float* __restrict__ W2ue2, float* __restrict__ X2ue,
    float* __restrict__ Yb8)
{
  __shared__ float As[32][68], Bs[32][68];
  int t = threadIdx.x, u0 = blockIdx.x*64, y = blockIdx.y;
  int z = y>>1, h0 = (y&1)*64;
  const float* W = (z == 0) ? W2ue1 : W2ue2;
  int coff = (z == 2) ? H2 : 0;
  float* op; int ldo;
  if      (z == 0){ op = X2ue + h0;     ldo = H2; }
  else if (z == 1){ op = X2ue + H + h0; ldo = H2; }
  else            { op = Yb8 + h0;      ldo = H;  }
  int tx = t&15, ty = t>>4;
  int hr = t>>2, c0 = (t&3)*8;     // both stagings: 64 rows x 4 thr, 8 k each
  float acc[4][4] = {};
  for (int kc=0; kc<H2; kc+=32){
    float w8[8], x8[8];
    const float* wr = W + (size_t)(h0+hr)*(2*H2) + coff + kc + c0;
    #pragma unroll
    for (int i=0;i<8;i++) w8[i] = wr[i];
    const float* xr = Xue + (size_t)(u0+hr)*H2 + kc + c0;
    bool uok = (u0+hr < UEN);
    #pragma unroll
    for (int i=0;i<8;i++) x8[i] = uok ? xr[i] : 0.f;
    __syncthreads();
    #pragma unroll
    for (int i=0;i<8;i++) As[c0+i][hr] = w8[i];
    #pragma unroll
    for (int i=0;i<8;i++) Bs[c0+i][hr] = x8[i];
    __syncthreads();
    tile_core(As, Bs, tx, ty, acc);
  }
  #pragma unroll
  for (int j=0;j<4;j++){
    int u = u0 + tx*4 + j;
    if (u < UEN){
      #pragma unroll
      for (int i=0;i<4;i++) op[(size_t)u*ldo + ty*4 + i] = acc[i][j];
    }
  }
}

// ---------------- Xue assemble: x3 = T3 + P3 gather; x4 = T4 + R4 gather ----------------
__global__ __launch_bounds__(256) void k_x_ueB(
    const float* __restrict__ T3, const float* __restrict__ T4,
    const float* __restrict__ P3t, const float* __restrict__ R4,
    const int* __restrict__ adj_ue, const int* __restrict__ ue2ue,
    float* __restrict__ Xue)
{
  __shared__ int aj[SS], u2[SS];
  int u = blockIdx.x, t = threadIdx.x;
  if (t < SS){ aj[t] = adj_ue[u*SS+t]; u2[t] = ue2ue[u*SS+t]; }
  __syncthreads();
  int h = t & (H-1);
  float g, s = 0.f;
  if (t < H){
    g = T3[(size_t)u*H + h];
    for (int q=0;q<SS;q++) s += P3t[(size_t)aj[q]*H + h];
  } else {
    g = T4[(size_t)u*H + h];
    for (int q=0;q<SS;q++) s += R4[(size_t)u2[q]*H + h];
  }
  Xue[(size_t)u*H2 + t] = frelu(g + s*INV_NEIGH);
}

// ---------------- X_ap assemble ----------------
__global__ __launch_bounds__(256) void k_x_ap(
    const float* __restrict__ RA, const float* __restrict__ U1,
    const int* __restrict__ adj_ap, const int* __restrict__ ap2ap,
    float* __restrict__ Xap)
{
  __shared__ int aj[SS], a2[SS];
  int i = blockIdx.x, t = threadIdx.x;
  if (t < SS){ aj[t] = adj_ap[i*SS+t]; a2[t] = ap2ap[i*SS+t]; }
  __syncthreads();
  int h = t & (H-1);
  float g, s = 0.f;
  if (t < H){
    g = RA[(size_t)i*H + h];                               // G1
    for (int q=0;q<SS;q++) s += U1[(size_t)aj[q]*H + h];
  } else {
    g = RA[(size_t)APN*H + (size_t)i*H + h];               // G2a
    const float* Q2t = RA + (size_t)2*APN*H;
    for (int q=0;q<SS;q++) s += Q2t[(size_t)a2[q]*H + h];
  }
  Xap[(size_t)i*H2 + t] = frelu(g + s*INV_NEIGH);
}

// ---------------- P7 ----------------
__global__ __launch_bounds__(128) void k_p7(
    const float* __restrict__ Xap, const float* __restrict__ W2ue1,
    float* __restrict__ P7t)
{
  __shared__ float xrow[H2];
  int n = blockIdx.x, t = threadIdx.x;
  xrow[t] = Xap[(size_t)n*H2 + t];
  xrow[t+128] = Xap[(size_t)n*H2 + t + 128];
  __syncthreads();
  const float* w = W2ue1 + (size_t)t*(2*H2) + H2;
  float s0=0.f,s1=0.f,s2=0.f,s3=0.f;
  for (int c=0;c<H2;c+=4){
    s0 = fmaf(w[c  ], xrow[c  ], s0);
    s1 = fmaf(w[c+1], xrow[c+1], s1);
    s2 = fmaf(w[c+2], xrow[c+2], s2);
    s3 = fmaf(w[c+3], xrow[c+3], s3);
  }
  P7t[(size_t)n*H + t] = (s0+s1)+(s2+s3);
}

// ---------------- x7/x8 assemble ----------------
__global__ __launch_bounds__(256) void k_x7x8b(
    float* __restrict__ X2ue, const float* __restrict__ P7t,
    const float* __restrict__ Yb8, const int* __restrict__ adj_ue,
    const int* __restrict__ ue2ue)
{
  __shared__ int aj[SS], u2[SS];
  int u = blockIdx.x, t = threadIdx.x;
  if (t < SS){ aj[t] = adj_ue[u*SS+t]; u2[t] = ue2ue[u*SS+t]; }
  __syncthreads();
  float g = X2ue[(size_t)u*H2 + t];
  float s = 0.f;
  if (t < H){
    for (int q=0;q<SS;q++) s += P7t[(size_t)aj[q]*H + t];
  } else {
    for (int q=0;q<SS;q++) s += Yb8[(size_t)u2[q]*H + (t-H)];
  }
  X2ue[(size_t)u*H2 + t] = frelu(g + s*INV_NEIGH);
}

// ---------------- AP layer 2 + PC head ----------------
__global__ __launch_bounds__(256) void k_ap_layer2_head(
    const float* __restrict__ Xap, const float* __restrict__ Xue,
    const float* __restrict__ W2ap1, const float* __restrict__ W2ap2,
    const int* __restrict__ adj_ap, const int* __restrict__ ap2ap,
    const float* __restrict__ wap1, const float* __restrict__ wap2,
    const float* __restrict__ bais_ap, float* __restrict__ out_pc)
{
  __shared__ float xa[H2], a5[H2], a6[H2], xs2[H2], red[256];
  __shared__ int aj[SS], a2i[SS];
  int i = blockIdx.x, t = threadIdx.x;
  if (t < SS){ aj[t] = adj_ap[i*SS+t]; a2i[t] = ap2ap[i*SS+t]; }
  __syncthreads();
  xa[t] = Xap[(size_t)i*H2+t];
  float s5=0.f, s6=0.f;
  for (int q=0;q<SS;q++){
    s5 += Xue[(size_t)aj[q]*H2 + t];
    s6 += Xap[(size_t)a2i[q]*H2 + t];
  }
  a5[t]=s5*INV_NEIGH; a6[t]=s6*INV_NEIGH;
  __syncthreads();
  const float* w; const float* agg;
  if (t < H){ w = W2ap1 + (size_t)t*(2*H2);     agg = a5; }
  else      { w = W2ap2 + (size_t)(t-H)*(2*H2); agg = a6; }
  float s0=0.f,s1=0.f,s2=0.f,s3=0.f;
  for (int c=0;c<H2;c+=4){
    s0 = fmaf(w[c  ], xa[c  ], s0);
    s1 = fmaf(w[c+1], xa[c+1], s1);
    s2 = fmaf(w[c+2], xa[c+2], s2);
    s3 = fmaf(w[c+3], xa[c+3], s3);
  }
  for (int c=0;c<H2;c+=4){
    s0 = fmaf(w[H2+c  ], agg[c  ], s0);
    s1 = fmaf(w[H2+c+1], agg[c+1], s1);
    s2 = fmaf(w[H2+c+2], agg[c+2], s2);
    s3 = fmaf(w[H2+c+3], agg[c+3], s3);
  }
  xs2[t] = frelu((s0+s1)+(s2+s3));
  __syncthreads();
  float hid = bais_ap[i];
  const float* wr1 = wap1 + (size_t)t*H2;
  for (int c=0;c<H2;c++) hid = fmaf(wr1[c], xs2[c], hid);
  red[t] = wap2[t]*hid;
  __syncthreads();
  for (int o=128;o>0;o>>=1){ if (t<o) red[t]+=red[t+o]; __syncthreads(); }
  if (t==0) out_pc[i] = 1.f/(1.f+expf(-red[0]));
}

// ---------------- BatchNorm ----------------
__global__ __launch_bounds__(256) void k_bn_part(const float* __restrict__ X2ue,
                                                 float* __restrict__ part){
  int b = blockIdx.x, c = threadIdx.x;
  float s=0.f, s2=0.f;
  for (int u = b*125; u < (b+1)*125; u++){
    float v = X2ue[(size_t)u*H2 + c];
    s += v; s2 += v*v;
  }
  part[b*512 + c] = s;
  part[b*512 + 256 + c] = s2;
}

__global__ __launch_bounds__(256) void k_bn_final(
    const float* __restrict__ part, const float* __restrict__ gamma,
    const float* __restrict__ beta, const float* __restrict__ wue,
    float* __restrict__ scsh, float* __restrict__ out_scalar)
{
  __shared__ float red[256];
  int t = threadIdx.x;
  float s=0.f, s2=0.f;
  for (int b=0;b<32;b++){ s += part[b*512+t]; s2 += part[b*512+256+t]; }
  float mean = s*(1.f/UEN);
  float var  = s2*(1.f/UEN) - mean*mean;
  float sc = gamma[t]*rsqrtf(var + 1e-5f);
  scsh[t]    = sc;
  scsh[H2+t] = beta[t] - mean*sc;
  float vsum = 0.f;
  if (t < APN){
    const float* wr = wue + (size_t)t*H2;
    float S=0.f, S2=0.f;
    for (int c=0;c<H2;c++){ float w=wr[c]; S+=w; S2+=w*w; }
    vsum = (S2 - S*S*(1.f/H2)) * (1.f/(H2-1));
  }
  red[t]=vsum; __syncthreads();
  for (int o=128;o>0;o>>=1){ if (t<o) red[t]+=red[t+o]; __syncthreads(); }
  if (t==0) out_scalar[0]=red[0];
}

// ---------------- UA head (BN affine on load) ----------------
__global__ __launch_bounds__(128) void k_ua_head(
    const float* __restrict__ X2ue, const float* __restrict__ scsh,
    const float* __restrict__ wue, const float* __restrict__ bais_ue,
    float* __restrict__ out)
{
  __shared__ float xs[4][H2];
  __shared__ float rmax[128], rmin[128], rs1[128], rs2[128];
  int u0 = blockIdx.x*4, t = threadIdx.x;
  #pragma unroll
  for (int q=0;q<4;q++){
    xs[q][t]     = X2ue[(size_t)(u0+q)*H2 + t]*scsh[t] + scsh[H2+t];
    xs[q][t+128] = X2ue[(size_t)(u0+q)*H2 + t + 128]*scsh[t+128] + scsh[H2+t+128];
  }
  __syncthreads();
  int a = t;
  float acc[4] = {0.f,0.f,0.f,0.f};
  if (a < APN){
    const float* wr = wue + (size_t)a*H2;
    for (int c=0;c<H2;c++){
      float w = wr[c];
      acc[0] = fmaf(w, xs[0][c], acc[0]);
      acc[1] = fmaf(w, xs[1][c], acc[1]);
      acc[2] = fmaf(w, xs[2][c], acc[2]);
      acc[3] = fmaf(w, xs[3][c], acc[3]);
    }
    #pragma unroll
    for (int q=0;q<4;q++) acc[q] += bais_ue[u0+q];
  }
  for (int q=0;q<4;q++){
    rmax[t] = (a<APN) ? acc[q] : -FLT_MAX;
    rmin[t] = (a<APN) ? acc[q] :  FLT_MAX;
    __syncthreads();
    for (int o=64;o>0;o>>=1){
      if (t<o){ rmax[t]=fmaxf(rmax[t],rmax[t+o]); rmin[t]=fminf(rmin[t],rmin[t+o]); }
      __syncthreads();
    }
    float mx = rmax[0], mn = rmin[0];
    __syncthreads();
    float nor = (a<APN) ? (acc[q]-mx)/(mx-mn) : 0.f;
    float e1 = (a<APN) ? expf(nor*1000.f) : 0.f;
    float e2 = (a<APN) ? expf(nor)        : 0.f;
    rs1[t]=e1; rs2[t]=e2;
    __syncthreads();
    for (int o=64;o>0;o>>=1){
      if (t<o){ rs1[t]+=rs1[t+o]; rs2[t]+=rs2[t+o]; }
      __syncthreads();
    }
    float s1=rs1[0], s2=rs2[0];
    __syncthreads();
    if (a<APN){
      size_t u = u0+q;
      out[u*APN + a]                     = acc[q];   // UA_ori
      out[(size_t)UEN*APN   + u*APN + a] = e1/s1;    // UA_de
      out[(size_t)2*UEN*APN + u*APN + a] = e2/s2;    // UA_st
    }
  }
}

extern "C" void kernel_launch(void* const* d_in, const int* in_sizes, int n_in,
                              void* d_out, int out_size, void* d_ws, size_t ws_size,
                              hipStream_t stream) {
  const float* pl      = (const float*)d_in[0];
  const int*   adj_ue  = (const int*)d_in[2];
  const int*   adj_ap  = (const int*)d_in[3];
  const float* W1ap1   = (const float*)d_in[4];
  const float* W1ap2   = (const float*)d_in[5];
  const float* W1ue1   = (const float*)d_in[6];
  const float* W1ue2   = (const float*)d_in[7];
  const float* W2ap1   = (const float*)d_in[8];
  const float* W2ap2   = (const float*)d_in[9];
  const float* W2ue1   = (const float*)d_in[10];
  const float* W2ue2   = (const float*)d_in[11];
  const float* wap1    = (const float*)d_in[12];
  const float* wap2    = (const float*)d_in[13];
  const float* bais_ap = (const float*)d_in[14];
  const float* wue     = (const float*)d_in[15];
  const float* bais_ue = (const float*)d_in[16];
  const float* gamma   = (const float*)d_in[17];
  const float* beta    = (const float*)d_in[18];
  float* out = (float*)d_out;
  (void)in_sizes; (void)n_in; (void)out_size; (void)ws_size;

  char* ws = (char*)d_ws;
  size_t off = 0;
  auto alloc = [&](size_t bytes)->char*{
    char* p = ws + off; off += (bytes + 255) & ~(size_t)255; return p;
  };
  int*   ap2ap = (int*)alloc(APN*SS*4);
  int*   ue2ue = (int*)alloc(UEN*SS*4);
  float* Xap   = (float*)alloc((size_t)APN*H2*4);
  float* Xue   = (float*)alloc((size_t)UEN*H2*4);   // phase1: gemA partials
  float* X2ue  = (float*)alloc((size_t)UEN*H2*4);   // phase1: T3|T4
  float* part  = (float*)alloc(32*512*4);
  float* scsh  = (float*)alloc(2*H2*4);
  // ws-buffer aliases (dead-before-write ordering):
  float* partialA = Xue;               // 16*105*128 fl, dead after k_redA
  float* T3 = X2ue;                    // 512,000 fl, dead after k_x_ueB
  float* T4 = X2ue + 512000;           // 512,000 fl, dead after k_x_ueB
  // d_out scratch map (floats; out_size = 1,260,106; all dead before final writes):
  float* U1  = out;                    // 512,000; dead after k_x_ap
  float* Yb8 = out;                    // aliases U1 (k_gemC2 runs after k_x_ap)
  float* R4  = out + 520000;           // 512,000; dead after k_x_ueB
  float* RA  = out + 1040000;          // 4*105*128 (G1,G2a,Q2,P3)
  float* P3t = RA + (size_t)3*APN*H;
  float* P7t = out + 1100000;          // 13,440

  k_twohop        <<<dim3(((APN+UEN)*SS+255)/256), 256, 0, stream>>>(adj_ue, adj_ap, ap2ap, ue2ue);
  k_gemA4         <<<dim3(APN,4,4), 128, 0, stream>>>(pl, W1ap1, W1ap2, W1ue1, partialA);
  k_redA          <<<dim3((4*APN*H+255)/256), 256, 0, stream>>>(partialA, RA);
  k_gemB2         <<<dim3((UEN+63)/64, 8), 256, 0, stream>>>(pl, W1ap1, W1ue1, W1ue2,
                                                             T3, T4, U1, R4);
  k_x_ueB         <<<dim3(UEN), 256, 0, stream>>>(T3, T4, P3t, R4, adj_ue, ue2ue, Xue);
  k_x_ap          <<<dim3(APN), 256, 0, stream>>>(RA, U1, adj_ap, ap2ap, Xap);
  k_p7            <<<dim3(APN), 128, 0, stream>>>(Xap, W2ue1, P7t);
  k_gemC2         <<<dim3((UEN+63)/64, 6), 256, 0, stream>>>(Xue, W2ue1, W2ue2, X2ue, Yb8);
  k_ap_layer2_head<<<dim3(APN), 256, 0, stream>>>(Xap, Xue, W2ap1, W2ap2, adj_ap, ap2ap,
                                                  wap1, wap2, bais_ap,
                                                  out + (size_t)3*UEN*APN);
  k_x7x8b         <<<dim3(UEN), 256, 0, stream>>>(X2ue, P7t, Yb8, adj_ue, ue2ue);
  k_bn_part       <<<dim3(32), 256, 0, stream>>>(X2ue, part);
  k_bn_final      <<<dim3(1), 256, 0, stream>>>(part, gamma, beta, wue, scsh,
                                                out + (size_t)3*UEN*APN + APN);
  k_ua_head       <<<dim3(UEN/4), 128, 0, stream>>>(X2ue, scsh, wue, bais_ue, out);
}

// Round 10
// 326.279 us; speedup vs baseline: 1.8632x; 1.8632x over previous
//
#include <hip/hip_runtime.h>
#include <math.h>
#include <float.h>

// Round 10: round 9 with the register-spill fixed. tile_core now uses scalar
// LDS reads + #pragma unroll 4 (bounded live values). Round-9's full unroll
// with float4 LDS reads ballooned to 256 VGPR -> 850MB/launch spill traffic.
// All math and the scratch map identical to round 9 (which verified green).

#define APN 105
#define UEN 4000
#define H   128
#define H2  256
#define SS  10
#define INV_NEIGH (1.0f/11.0f)

__device__ __forceinline__ float frelu(float v){ return v > 0.f ? v : 0.f; }

// ---------------- two-hop indices ----------------
__global__ void k_twohop(const int* __restrict__ adj_ue, const int* __restrict__ adj_ap,
                         int* __restrict__ ap2ap, int* __restrict__ ue2ue){
  int idx = blockIdx.x*256 + threadIdx.x;
  if (idx >= (APN+UEN)*SS) return;
  if (idx < APN*SS){
    int s = idx % SS;
    ap2ap[idx] = adj_ue[adj_ap[idx]*SS + s];
  } else {
    int j = idx - APN*SS;
    int s = j % SS;
    ue2ue[j] = adj_ap[adj_ue[j]*SS + s];
  }
}

// ---------------- Family A: 4 slices x 4 K-splits over K=4000, n<APN ----------------
__global__ __launch_bounds__(128) void k_gemA4(
    const float* __restrict__ pl, const float* __restrict__ W1ap1,
    const float* __restrict__ W1ap2, const float* __restrict__ W1ue1,
    float* __restrict__ partial)
{
  __shared__ float plrow[1000];
  int n = blockIdx.x, slice = blockIdx.y, ks = blockIdx.z, t = threadIdx.x;
  int k0 = ks*1000;
  for (int j=t; j<1000; j+=128) plrow[j] = pl[(size_t)n*UEN + k0 + j];
  __syncthreads();
  const float* w; int lda;
  if      (slice == 0){ w = W1ap1;       lda = UEN+APN; }
  else if (slice == 1){ w = W1ap2;       lda = 2*UEN;   }
  else if (slice == 2){ w = W1ap2 + UEN; lda = 2*UEN;   }
  else                { w = W1ue1 + APN; lda = UEN+APN; }
  const float* wr = w + (size_t)t*lda + k0;
  float s0=0.f,s1=0.f,s2=0.f,s3=0.f;
  for (int j=0;j<1000;j+=4){
    s0 = fmaf(wr[j  ], plrow[j  ], s0);
    s1 = fmaf(wr[j+1], plrow[j+1], s1);
    s2 = fmaf(wr[j+2], plrow[j+2], s2);
    s3 = fmaf(wr[j+3], plrow[j+3], s3);
  }
  partial[((size_t)(slice*4+ks)*APN + n)*H + t] = (s0+s1)+(s2+s3);
}

__global__ __launch_bounds__(256) void k_redA(const float* __restrict__ partial,
                                              float* __restrict__ RA){
  int idx = blockIdx.x*256 + threadIdx.x;
  if (idx >= 4*APN*H) return;
  int slice = idx / (APN*H), r = idx % (APN*H);
  float s = 0.f;
  #pragma unroll
  for (int ks=0;ks<4;ks++) s += partial[((size_t)(slice*4+ks)*APN*H) + r];
  RA[idx] = s;
}

// ---------------- tiled GEMM inner core: 32-k chunk, 4x4 micro-tile ----------------
// Scalar LDS reads + capped unroll => bounded register pressure (the round-9
// float4 + full-unroll version spilled at 256 VGPR).
__device__ __forceinline__ void tile_core(const float (*As)[68], const float (*Bs)[68],
                                          int tx, int ty, float acc[4][4])
{
  #pragma unroll 4
  for (int k=0;k<32;k++){
    float a0 = As[k][ty*4+0], a1 = As[k][ty*4+1];
    float a2 = As[k][ty*4+2], a3 = As[k][ty*4+3];
    float b0 = Bs[k][tx*4+0], b1 = Bs[k][tx*4+1];
    float b2 = Bs[k][tx*4+2], b3 = Bs[k][tx*4+3];
    acc[0][0]=fmaf(a0,b0,acc[0][0]); acc[0][1]=fmaf(a0,b1,acc[0][1]);
    acc[0][2]=fmaf(a0,b2,acc[0][2]); acc[0][3]=fmaf(a0,b3,acc[0][3]);
    acc[1][0]=fmaf(a1,b0,acc[1][0]); acc[1][1]=fmaf(a1,b1,acc[1][1]);
    acc[1][2]=fmaf(a1,b2,acc[1][2]); acc[1][3]=fmaf(a1,b3,acc[1][3]);
    acc[2][0]=fmaf(a2,b0,acc[2][0]); acc[2][1]=fmaf(a2,b1,acc[2][1]);
    acc[2][2]=fmaf(a2,b2,acc[2][2]); acc[2][3]=fmaf(a2,b3,acc[2][3]);
    acc[3][0]=fmaf(a3,b0,acc[3][0]); acc[3][1]=fmaf(a3,b1,acc[3][1]);
    acc[3][2]=fmaf(a3,b2,acc[3][2]); acc[3][3]=fmaf(a3,b3,acc[3][3]);
  }
}

// ---------------- Family B tiled: K=105 (padded 128), 4 slices, grid (63, 8) ----------------
__global__ __launch_bounds__(256) void k_gemB2(
    const float* __restrict__ pl, const float* __restrict__ W1ap1,
    const float* __restrict__ W1ue1, const float* __restrict__ W1ue2,
    float* __restrict__ T3, float* __restrict__ T4,
    float* __restrict__ U1, float* __restrict__ R4)
{
  __shared__ float As[32][68], Bs[32][68];
  int t = threadIdx.x, u0 = blockIdx.x*64, y = blockIdx.y;
  int z = y>>1, h0 = (y&1)*64;
  const float* w; int lda; float* op;
  if      (z == 0){ w = W1ue1;       lda = UEN+APN; op = T3; }
  else if (z == 1){ w = W1ue2;       lda = 2*APN;   op = T4; }
  else if (z == 2){ w = W1ap1 + UEN; lda = UEN+APN; op = U1; }
  else            { w = W1ue2 + APN; lda = 2*APN;   op = R4; }
  int tx = t&15, ty = t>>4;
  int hr = t>>2,  c0 = (t&3)*8;    // W staging: 64 rows x 4 thr, 8 k each
  int kr = t>>3, uu0 = (t&7)*8;    // X staging: 32 k-rows x 8 thr, 8 u each
  float acc[4][4] = {};
  for (int kc=0; kc<128; kc+=32){
    float w8[8], x8[8];
    const float* wr = w + (size_t)(h0+hr)*lda + kc + c0;
    #pragma unroll
    for (int i=0;i<8;i++) w8[i] = (kc+c0+i < APN) ? wr[i] : 0.f;
    const float* xr = pl + (size_t)(kc+kr)*UEN + u0 + uu0;
    #pragma unroll
    for (int i=0;i<8;i++)
      x8[i] = (kc+kr < APN && u0+uu0+i < UEN) ? xr[i] : 0.f;
    __syncthreads();
    #pragma unroll
    for (int i=0;i<8;i++) As[c0+i][hr] = w8[i];
    #pragma unroll
    for (int i=0;i<8;i++) Bs[kr][uu0+i] = x8[i];
    __syncthreads();
    tile_core(As, Bs, tx, ty, acc);
  }
  #pragma unroll
  for (int j=0;j<4;j++){
    int u = u0 + tx*4 + j;
    if (u < UEN){
      #pragma unroll
      for (int i=0;i<4;i++) op[(size_t)u*H + h0 + ty*4 + i] = acc[i][j];
    }
  }
}

// ---------------- Family C tiled: K=256, grid (63, 6) ----------------
__global__ __launch_bounds__(256) void k_gemC2(
    const float* __restrict__ Xue, const float* __restrict__ W2ue1,
    const float* __restrict__ W2ue2, float* __restrict__ X2ue,
    float* __restrict__ Yb8)
{
  __shared__ float As[32][68], Bs[32][68];
  int t = threadIdx.x, u0 = blockIdx.x*64, y = blockIdx.y;
  int z = y>>1, h0 = (y&1)*64;
  const float* W = (z == 0) ? W2ue1 : W2ue2;
  int coff = (z == 2) ? H2 : 0;
  float* op; int ldo;
  if      (z == 0){ op = X2ue + h0;     ldo = H2; }
  else if (z == 1){ op = X2ue + H + h0; ldo = H2; }
  else            { op = Yb8 + h0;      ldo = H;  }
  int tx = t&15, ty = t>>4;
  int hr = t>>2, c0 = (t&3)*8;     // both stagings: 64 rows x 4 thr, 8 k each
  float acc[4][4] = {};
  for (int kc=0; kc<H2; kc+=32){
    float w8[8], x8[8];
    const float* wr = W + (size_t)(h0+hr)*(2*H2) + coff + kc + c0;
    #pragma unroll
    for (int i=0;i<8;i++) w8[i] = wr[i];
    const float* xr = Xue + (size_t)(u0+hr)*H2 + kc + c0;
    bool uok = (u0+hr < UEN);
    #pragma unroll
    for (int i=0;i<8;i++) x8[i] = uok ? xr[i] : 0.f;
    __syncthreads();
    #pragma unroll
    for (int i=0;i<8;i++) As[c0+i][hr] = w8[i];
    #pragma unroll
    for (int i=0;i<8;i++) Bs[c0+i][hr] = x8[i];
    __syncthreads();
    tile_core(As, Bs, tx, ty, acc);
  }
  #pragma unroll
  for (int j=0;j<4;j++){
    int u = u0 + tx*4 + j;
    if (u < UEN){
      #pragma unroll
      for (int i=0;i<4;i++) op[(size_t)u*ldo + ty*4 + i] = acc[i][j];
    }
  }
}

// ---------------- Xue assemble: x3 = T3 + P3 gather; x4 = T4 + R4 gather ----------------
__global__ __launch_bounds__(256) void k_x_ueB(
    const float* __restrict__ T3, const float* __restrict__ T4,
    const float* __restrict__ P3t, const float* __restrict__ R4,
    const int* __restrict__ adj_ue, const int* __restrict__ ue2ue,
    float* __restrict__ Xue)
{
  __shared__ int aj[SS], u2[SS];
  int u = blockIdx.x, t = threadIdx.x;
  if (t < SS){ aj[t] = adj_ue[u*SS+t]; u2[t] = ue2ue[u*SS+t]; }
  __syncthreads();
  int h = t & (H-1);
  float g, s = 0.f;
  if (t < H){
    g = T3[(size_t)u*H + h];
    for (int q=0;q<SS;q++) s += P3t[(size_t)aj[q]*H + h];
  } else {
    g = T4[(size_t)u*H + h];
    for (int q=0;q<SS;q++) s += R4[(size_t)u2[q]*H + h];
  }
  Xue[(size_t)u*H2 + t] = frelu(g + s*INV_NEIGH);
}

// ---------------- X_ap assemble ----------------
__global__ __launch_bounds__(256) void k_x_ap(
    const float* __restrict__ RA, const float* __restrict__ U1,
    const int* __restrict__ adj_ap, const int* __restrict__ ap2ap,
    float* __restrict__ Xap)
{
  __shared__ int aj[SS], a2[SS];
  int i = blockIdx.x, t = threadIdx.x;
  if (t < SS){ aj[t] = adj_ap[i*SS+t]; a2[t] = ap2ap[i*SS+t]; }
  __syncthreads();
  int h = t & (H-1);
  float g, s = 0.f;
  if (t < H){
    g = RA[(size_t)i*H + h];                               // G1
    for (int q=0;q<SS;q++) s += U1[(size_t)aj[q]*H + h];
  } else {
    g = RA[(size_t)APN*H + (size_t)i*H + h];               // G2a
    const float* Q2t = RA + (size_t)2*APN*H;
    for (int q=0;q<SS;q++) s += Q2t[(size_t)a2[q]*H + h];
  }
  Xap[(size_t)i*H2 + t] = frelu(g + s*INV_NEIGH);
}

// ---------------- P7 ----------------
__global__ __launch_bounds__(128) void k_p7(
    const float* __restrict__ Xap, const float* __restrict__ W2ue1,
    float* __restrict__ P7t)
{
  __shared__ float xrow[H2];
  int n = blockIdx.x, t = threadIdx.x;
  xrow[t] = Xap[(size_t)n*H2 + t];
  xrow[t+128] = Xap[(size_t)n*H2 + t + 128];
  __syncthreads();
  const float* w = W2ue1 + (size_t)t*(2*H2) + H2;
  float s0=0.f,s1=0.f,s2=0.f,s3=0.f;
  for (int c=0;c<H2;c+=4){
    s0 = fmaf(w[c  ], xrow[c  ], s0);
    s1 = fmaf(w[c+1], xrow[c+1], s1);
    s2 = fmaf(w[c+2], xrow[c+2], s2);
    s3 = fmaf(w[c+3], xrow[c+3], s3);
  }
  P7t[(size_t)n*H + t] = (s0+s1)+(s2+s3);
}

// ---------------- x7/x8 assemble ----------------
__global__ __launch_bounds__(256) void k_x7x8b(
    float* __restrict__ X2ue, const float* __restrict__ P7t,
    const float* __restrict__ Yb8, const int* __restrict__ adj_ue,
    const int* __restrict__ ue2ue)
{
  __shared__ int aj[SS], u2[SS];
  int u = blockIdx.x, t = threadIdx.x;
  if (t < SS){ aj[t] = adj_ue[u*SS+t]; u2[t] = ue2ue[u*SS+t]; }
  __syncthreads();
  float g = X2ue[(size_t)u*H2 + t];
  float s = 0.f;
  if (t < H){
    for (int q=0;q<SS;q++) s += P7t[(size_t)aj[q]*H + t];
  } else {
    for (int q=0;q<SS;q++) s += Yb8[(size_t)u2[q]*H + (t-H)];
  }
  X2ue[(size_t)u*H2 + t] = frelu(g + s*INV_NEIGH);
}

// ---------------- AP layer 2 + PC head ----------------
__global__ __launch_bounds__(256) void k_ap_layer2_head(
    const float* __restrict__ Xap, const float* __restrict__ Xue,
    const float* __restrict__ W2ap1, const float* __restrict__ W2ap2,
    const int* __restrict__ adj_ap, const int* __restrict__ ap2ap,
    const float* __restrict__ wap1, const float* __restrict__ wap2,
    const float* __restrict__ bais_ap, float* __restrict__ out_pc)
{
  __shared__ float xa[H2], a5[H2], a6[H2], xs2[H2], red[256];
  __shared__ int aj[SS], a2i[SS];
  int i = blockIdx.x, t = threadIdx.x;
  if (t < SS){ aj[t] = adj_ap[i*SS+t]; a2i[t] = ap2ap[i*SS+t]; }
  __syncthreads();
  xa[t] = Xap[(size_t)i*H2+t];
  float s5=0.f, s6=0.f;
  for (int q=0;q<SS;q++){
    s5 += Xue[(size_t)aj[q]*H2 + t];
    s6 += Xap[(size_t)a2i[q]*H2 + t];
  }
  a5[t]=s5*INV_NEIGH; a6[t]=s6*INV_NEIGH;
  __syncthreads();
  const float* w; const float* agg;
  if (t < H){ w = W2ap1 + (size_t)t*(2*H2);     agg = a5; }
  else      { w = W2ap2 + (size_t)(t-H)*(2*H2); agg = a6; }
  float s0=0.f,s1=0.f,s2=0.f,s3=0.f;
  for (int c=0;c<H2;c+=4){
    s0 = fmaf(w[c  ], xa[c  ], s0);
    s1 = fmaf(w[c+1], xa[c+1], s1);
    s2 = fmaf(w[c+2], xa[c+2], s2);
    s3 = fmaf(w[c+3], xa[c+3], s3);
  }
  for (int c=0;c<H2;c+=4){
    s0 = fmaf(w[H2+c  ], agg[c  ], s0);
    s1 = fmaf(w[H2+c+1], agg[c+1], s1);
    s2 = fmaf(w[H2+c+2], agg[c+2], s2);
    s3 = fmaf(w[H2+c+3], agg[c+3], s3);
  }
  xs2[t] = frelu((s0+s1)+(s2+s3));
  __syncthreads();
  float hid = bais_ap[i];
  const float* wr1 = wap1 + (size_t)t*H2;
  for (int c=0;c<H2;c++) hid = fmaf(wr1[c], xs2[c], hid);
  red[t] = wap2[t]*hid;
  __syncthreads();
  for (int o=128;o>0;o>>=1){ if (t<o) red[t]+=red[t+o]; __syncthreads(); }
  if (t==0) out_pc[i] = 1.f/(1.f+expf(-red[0]));
}

// ---------------- BatchNorm ----------------
__global__ __launch_bounds__(256) void k_bn_part(const float* __restrict__ X2ue,
                                                 float* __restrict__ part){
  int b = blockIdx.x, c = threadIdx.x;
  float s=0.f, s2=0.f;
  for (int u = b*125; u < (b+1)*125; u++){
    float v = X2ue[(size_t)u*H2 + c];
    s += v; s2 += v*v;
  }
  part[b*512 + c] = s;
  part[b*512 + 256 + c] = s2;
}

__global__ __launch_bounds__(256) void k_bn_final(
    const float* __restrict__ part, const float* __restrict__ gamma,
    const float* __restrict__ beta, const float* __restrict__ wue,
    float* __restrict__ scsh, float* __restrict__ out_scalar)
{
  __shared__ float red[256];
  int t = threadIdx.x;
  float s=0.f, s2=0.f;
  for (int b=0;b<32;b++){ s += part[b*512+t]; s2 += part[b*512+256+t]; }
  float mean = s*(1.f/UEN);
  float var  = s2*(1.f/UEN) - mean*mean;
  float sc = gamma[t]*rsqrtf(var + 1e-5f);
  scsh[t]    = sc;
  scsh[H2+t] = beta[t] - mean*sc;
  float vsum = 0.f;
  if (t < APN){
    const float* wr = wue + (size_t)t*H2;
    float S=0.f, S2=0.f;
    for (int c=0;c<H2;c++){ float w=wr[c]; S+=w; S2+=w*w; }
    vsum = (S2 - S*S*(1.f/H2)) * (1.f/(H2-1));
  }
  red[t]=vsum; __syncthreads();
  for (int o=128;o>0;o>>=1){ if (t<o) red[t]+=red[t+o]; __syncthreads(); }
  if (t==0) out_scalar[0]=red[0];
}

// ---------------- UA head (BN affine on load) ----------------
__global__ __launch_bounds__(128) void k_ua_head(
    const float* __restrict__ X2ue, const float* __restrict__ scsh,
    const float* __restrict__ wue, const float* __restrict__ bais_ue,
    float* __restrict__ out)
{
  __shared__ float xs[4][H2];
  __shared__ float rmax[128], rmin[128], rs1[128], rs2[128];
  int u0 = blockIdx.x*4, t = threadIdx.x;
  #pragma unroll
  for (int q=0;q<4;q++){
    xs[q][t]     = X2ue[(size_t)(u0+q)*H2 + t]*scsh[t] + scsh[H2+t];
    xs[q][t+128] = X2ue[(size_t)(u0+q)*H2 + t + 128]*scsh[t+128] + scsh[H2+t+128];
  }
  __syncthreads();
  int a = t;
  float acc[4] = {0.f,0.f,0.f,0.f};
  if (a < APN){
    const float* wr = wue + (size_t)a*H2;
    for (int c=0;c<H2;c++){
      float w = wr[c];
      acc[0] = fmaf(w, xs[0][c], acc[0]);
      acc[1] = fmaf(w, xs[1][c], acc[1]);
      acc[2] = fmaf(w, xs[2][c], acc[2]);
      acc[3] = fmaf(w, xs[3][c], acc[3]);
    }
    #pragma unroll
    for (int q=0;q<4;q++) acc[q] += bais_ue[u0+q];
  }
  for (int q=0;q<4;q++){
    rmax[t] = (a<APN) ? acc[q] : -FLT_MAX;
    rmin[t] = (a<APN) ? acc[q] :  FLT_MAX;
    __syncthreads();
    for (int o=64;o>0;o>>=1){
      if (t<o){ rmax[t]=fmaxf(rmax[t],rmax[t+o]); rmin[t]=fminf(rmin[t],rmin[t+o]); }
      __syncthreads();
    }
    float mx = rmax[0], mn = rmin[0];
    __syncthreads();
    float nor = (a<APN) ? (acc[q]-mx)/(mx-mn) : 0.f;
    float e1 = (a<APN) ? expf(nor*1000.f) : 0.f;
    float e2 = (a<APN) ? expf(nor)        : 0.f;
    rs1[t]=e1; rs2[t]=e2;
    __syncthreads();
    for (int o=64;o>0;o>>=1){
      if (t<o){ rs1[t]+=rs1[t+o]; rs2[t]+=rs2[t+o]; }
      __syncthreads();
    }
    float s1=rs1[0], s2=rs2[0];
    __syncthreads();
    if (a<APN){
      size_t u = u0+q;
      out[u*APN + a]                     = acc[q];   // UA_ori
      out[(size_t)UEN*APN   + u*APN + a] = e1/s1;    // UA_de
      out[(size_t)2*UEN*APN + u*APN + a] = e2/s2;    // UA_st
    }
  }
}

extern "C" void kernel_launch(void* const* d_in, const int* in_sizes, int n_in,
                              void* d_out, int out_size, void* d_ws, size_t ws_size,
                              hipStream_t stream) {
  const float* pl      = (const float*)d_in[0];
  const int*   adj_ue  = (const int*)d_in[2];
  const int*   adj_ap  = (const int*)d_in[3];
  const float* W1ap1   = (const float*)d_in[4];
  const float* W1ap2   = (const float*)d_in[5];
  const float* W1ue1   = (const float*)d_in[6];
  const float* W1ue2   = (const float*)d_in[7];
  const float* W2ap1   = (const float*)d_in[8];
  const float* W2ap2   = (const float*)d_in[9];
  const float* W2ue1   = (const float*)d_in[10];
  const float* W2ue2   = (const float*)d_in[11];
  const float* wap1    = (const float*)d_in[12];
  const float* wap2    = (const float*)d_in[13];
  const float* bais_ap = (const float*)d_in[14];
  const float* wue     = (const float*)d_in[15];
  const float* bais_ue = (const float*)d_in[16];
  const float* gamma   = (const float*)d_in[17];
  const float* beta    = (const float*)d_in[18];
  float* out = (float*)d_out;
  (void)in_sizes; (void)n_in; (void)out_size; (void)ws_size;

  char* ws = (char*)d_ws;
  size_t off = 0;
  auto alloc = [&](size_t bytes)->char*{
    char* p = ws + off; off += (bytes + 255) & ~(size_t)255; return p;
  };
  int*   ap2ap = (int*)alloc(APN*SS*4);
  int*   ue2ue = (int*)alloc(UEN*SS*4);
  float* Xap   = (float*)alloc((size_t)APN*H2*4);
  float* Xue   = (float*)alloc((size_t)UEN*H2*4);   // phase1: gemA partials
  float* X2ue  = (float*)alloc((size_t)UEN*H2*4);   // phase1: T3|T4
  float* part  = (float*)alloc(32*512*4);
  float* scsh  = (float*)alloc(2*H2*4);
  // ws-buffer aliases (dead-before-write ordering):
  float* partialA = Xue;               // 16*105*128 fl, dead after k_redA
  float* T3 = X2ue;                    // 512,000 fl, dead after k_x_ueB
  float* T4 = X2ue + 512000;           // 512,000 fl, dead after k_x_ueB
  // d_out scratch map (floats; out_size = 1,260,106; all dead before final writes):
  float* U1  = out;                    // 512,000; dead after k_x_ap
  float* Yb8 = out;                    // aliases U1 (k_gemC2 runs after k_x_ap)
  float* R4  = out + 520000;           // 512,000; dead after k_x_ueB
  float* RA  = out + 1040000;          // 4*105*128 (G1,G2a,Q2,P3)
  float* P3t = RA + (size_t)3*APN*H;
  float* P7t = out + 1100000;          // 13,440

  k_twohop        <<<dim3(((APN+UEN)*SS+255)/256), 256, 0, stream>>>(adj_ue, adj_ap, ap2ap, ue2ue);
  k_gemA4         <<<dim3(APN,4,4), 128, 0, stream>>>(pl, W1ap1, W1ap2, W1ue1, partialA);
  k_redA          <<<dim3((4*APN*H+255)/256), 256, 0, stream>>>(partialA, RA);
  k_gemB2         <<<dim3((UEN+63)/64, 8), 256, 0, stream>>>(pl, W1ap1, W1ue1, W1ue2,
                                                             T3, T4, U1, R4);
  k_x_ueB         <<<dim3(UEN), 256, 0, stream>>>(T3, T4, P3t, R4, adj_ue, ue2ue, Xue);
  k_x_ap          <<<dim3(APN), 256, 0, stream>>>(RA, U1, adj_ap, ap2ap, Xap);
  k_p7            <<<dim3(APN), 128, 0, stream>>>(Xap, W2ue1, P7t);
  k_gemC2         <<<dim3((UEN+63)/64, 6), 256, 0, stream>>>(Xue, W2ue1, W2ue2, X2ue, Yb8);
  k_ap_layer2_head<<<dim3(APN), 256, 0, stream>>>(Xap, Xue, W2ap1, W2ap2, adj_ap, ap2ap,
                                                  wap1, wap2, bais_ap,
                                                  out + (size_t)3*UEN*APN);
  k_x7x8b         <<<dim3(UEN), 256, 0, stream>>>(X2ue, P7t, Yb8, adj_ue, ue2ue);
  k_bn_part       <<<dim3(32), 256, 0, stream>>>(X2ue, part);
  k_bn_final      <<<dim3(1), 256, 0, stream>>>(part, gamma, beta, wue, scsh,
                                                out + (size_t)3*UEN*APN + APN);
  k_ua_head       <<<dim3(UEN/4), 128, 0, stream>>>(X2ue, scsh, wue, bais_ue, out);
}

// Round 11
// 319.792 us; speedup vs baseline: 1.9010x; 1.0203x over previous
//
#include <hip/hip_runtime.h>
#include <math.h>
#include <float.h>

// Round 11: family-A GEMM n-tiled (NT=7 n per block, KC=250 k-chunks, 16-way
// k-split). Fixes the 28x weight re-read + latency-bound profile of k_gemA4
// (93us, FETCH 36MB, VALUBusy 11%). All other kernels identical to round 10.

#define APN 105
#define UEN 4000
#define H   128
#define H2  256
#define SS  10
#define INV_NEIGH (1.0f/11.0f)
#define NT 7
#define KC 250
#define NKS 16

__device__ __forceinline__ float frelu(float v){ return v > 0.f ? v : 0.f; }

// ---------------- two-hop indices ----------------
__global__ void k_twohop(const int* __restrict__ adj_ue, const int* __restrict__ adj_ap,
                         int* __restrict__ ap2ap, int* __restrict__ ue2ue){
  int idx = blockIdx.x*256 + threadIdx.x;
  if (idx >= (APN+UEN)*SS) return;
  if (idx < APN*SS){
    int s = idx % SS;
    ap2ap[idx] = adj_ue[adj_ap[idx]*SS + s];
  } else {
    int j = idx - APN*SS;
    int s = j % SS;
    ue2ue[j] = adj_ap[adj_ue[j]*SS + s];
  }
}

// ---------------- Family A: n-tiled, 4 slices x 16 k-splits, grid (15,4,16) ----------------
// slice0 G1 = W1ap1[:, :4000]   slice1 G2a = W1ap2[:, :4000]
// slice2 Q2 = W1ap2[:, 4000:]   slice3 P3  = W1ue1[:, 105:]
__global__ __launch_bounds__(128) void k_gemA5(
    const float* __restrict__ pl, const float* __restrict__ W1ap1,
    const float* __restrict__ W1ap2, const float* __restrict__ W1ue1,
    float* __restrict__ partial)
{
  __shared__ float pls[NT][KC];
  int nt = blockIdx.x, slice = blockIdx.y, ks = blockIdx.z, t = threadIdx.x;
  int n0 = nt*NT, k0 = ks*KC;
  for (int e = t; e < NT*KC; e += 128){
    int i = e / KC, j = e - i*KC;
    pls[i][j] = pl[(size_t)(n0+i)*UEN + k0 + j];
  }
  __syncthreads();
  const float* w; int lda;
  if      (slice == 0){ w = W1ap1;       lda = UEN+APN; }
  else if (slice == 1){ w = W1ap2;       lda = 2*UEN;   }
  else if (slice == 2){ w = W1ap2 + UEN; lda = 2*UEN;   }
  else                { w = W1ue1 + APN; lda = UEN+APN; }
  const float* wr = w + (size_t)t*lda + k0;
  float acc[NT];
  #pragma unroll
  for (int i=0;i<NT;i++) acc[i] = 0.f;
  #pragma unroll 2
  for (int j=0;j<KC;j++){
    float wv = wr[j];
    #pragma unroll
    for (int i=0;i<NT;i++) acc[i] = fmaf(wv, pls[i][j], acc[i]);
  }
  float* po = partial + (size_t)(slice*NKS+ks)*APN*H;
  #pragma unroll
  for (int i=0;i<NT;i++) po[(size_t)(n0+i)*H + t] = acc[i];
}

__global__ __launch_bounds__(256) void k_redA(const float* __restrict__ partial,
                                              float* __restrict__ RA){
  int idx = blockIdx.x*256 + threadIdx.x;
  if (idx >= 4*APN*H) return;
  int slice = idx / (APN*H), r = idx % (APN*H);
  float s = 0.f;
  #pragma unroll
  for (int ks=0;ks<NKS;ks++) s += partial[((size_t)(slice*NKS+ks)*APN*H) + r];
  RA[idx] = s;
}

// ---------------- tiled GEMM inner core: 32-k chunk, 4x4 micro-tile ----------------
__device__ __forceinline__ void tile_core(const float (*As)[68], const float (*Bs)[68],
                                          int tx, int ty, float acc[4][4])
{
  #pragma unroll 4
  for (int k=0;k<32;k++){
    float a0 = As[k][ty*4+0], a1 = As[k][ty*4+1];
    float a2 = As[k][ty*4+2], a3 = As[k][ty*4+3];
    float b0 = Bs[k][tx*4+0], b1 = Bs[k][tx*4+1];
    float b2 = Bs[k][tx*4+2], b3 = Bs[k][tx*4+3];
    acc[0][0]=fmaf(a0,b0,acc[0][0]); acc[0][1]=fmaf(a0,b1,acc[0][1]);
    acc[0][2]=fmaf(a0,b2,acc[0][2]); acc[0][3]=fmaf(a0,b3,acc[0][3]);
    acc[1][0]=fmaf(a1,b0,acc[1][0]); acc[1][1]=fmaf(a1,b1,acc[1][1]);
    acc[1][2]=fmaf(a1,b2,acc[1][2]); acc[1][3]=fmaf(a1,b3,acc[1][3]);
    acc[2][0]=fmaf(a2,b0,acc[2][0]); acc[2][1]=fmaf(a2,b1,acc[2][1]);
    acc[2][2]=fmaf(a2,b2,acc[2][2]); acc[2][3]=fmaf(a2,b3,acc[2][3]);
    acc[3][0]=fmaf(a3,b0,acc[3][0]); acc[3][1]=fmaf(a3,b1,acc[3][1]);
    acc[3][2]=fmaf(a3,b2,acc[3][2]); acc[3][3]=fmaf(a3,b3,acc[3][3]);
  }
}

// ---------------- Family B tiled: K=105 (padded 128), 4 slices, grid (63, 8) ----------------
__global__ __launch_bounds__(256) void k_gemB2(
    const float* __restrict__ pl, const float* __restrict__ W1ap1,
    const float* __restrict__ W1ue1, const float* __restrict__ W1ue2,
    float* __restrict__ T3, float* __restrict__ T4,
    float* __restrict__ U1, float* __restrict__ R4)
{
  __shared__ float As[32][68], Bs[32][68];
  int t = threadIdx.x, u0 = blockIdx.x*64, y = blockIdx.y;
  int z = y>>1, h0 = (y&1)*64;
  const float* w; int lda; float* op;
  if      (z == 0){ w = W1ue1;       lda = UEN+APN; op = T3; }
  else if (z == 1){ w = W1ue2;       lda = 2*APN;   op = T4; }
  else if (z == 2){ w = W1ap1 + UEN; lda = UEN+APN; op = U1; }
  else            { w = W1ue2 + APN; lda = 2*APN;   op = R4; }
  int tx = t&15, ty = t>>4;
  int hr = t>>2,  c0 = (t&3)*8;
  int kr = t>>3, uu0 = (t&7)*8;
  float acc[4][4] = {};
  for (int kc=0; kc<128; kc+=32){
    float w8[8], x8[8];
    const float* wr = w + (size_t)(h0+hr)*lda + kc + c0;
    #pragma unroll
    for (int i=0;i<8;i++) w8[i] = (kc+c0+i < APN) ? wr[i] : 0.f;
    const float* xr = pl + (size_t)(kc+kr)*UEN + u0 + uu0;
    #pragma unroll
    for (int i=0;i<8;i++)
      x8[i] = (kc+kr < APN && u0+uu0+i < UEN) ? xr[i] : 0.f;
    __syncthreads();
    #pragma unroll
    for (int i=0;i<8;i++) As[c0+i][hr] = w8[i];
    #pragma unroll
    for (int i=0;i<8;i++) Bs[kr][uu0+i] = x8[i];
    __syncthreads();
    tile_core(As, Bs, tx, ty, acc);
  }
  #pragma unroll
  for (int j=0;j<4;j++){
    int u = u0 + tx*4 + j;
    if (u < UEN){
      #pragma unroll
      for (int i=0;i<4;i++) op[(size_t)u*H + h0 + ty*4 + i] = acc[i][j];
    }
  }
}

// ---------------- Family C tiled: K=256, grid (63, 6) ----------------
__global__ __launch_bounds__(256) void k_gemC2(
    const float* __restrict__ Xue, const float* __restrict__ W2ue1,
    const float* __restrict__ W2ue2, float* __restrict__ X2ue,
    float* __restrict__ Yb8)
{
  __shared__ float As[32][68], Bs[32][68];
  int t = threadIdx.x, u0 = blockIdx.x*64, y = blockIdx.y;
  int z = y>>1, h0 = (y&1)*64;
  const float* W = (z == 0) ? W2ue1 : W2ue2;
  int coff = (z == 2) ? H2 : 0;
  float* op; int ldo;
  if      (z == 0){ op = X2ue + h0;     ldo = H2; }
  else if (z == 1){ op = X2ue + H + h0; ldo = H2; }
  else            { op = Yb8 + h0;      ldo = H;  }
  int tx = t&15, ty = t>>4;
  int hr = t>>2, c0 = (t&3)*8;
  float acc[4][4] = {};
  for (int kc=0; kc<H2; kc+=32){
    float w8[8], x8[8];
    const float* wr = W + (size_t)(h0+hr)*(2*H2) + coff + kc + c0;
    #pragma unroll
    for (int i=0;i<8;i++) w8[i] = wr[i];
    const float* xr = Xue + (size_t)(u0+hr)*H2 + kc + c0;
    bool uok = (u0+hr < UEN);
    #pragma unroll
    for (int i=0;i<8;i++) x8[i] = uok ? xr[i] : 0.f;
    __syncthreads();
    #pragma unroll
    for (int i=0;i<8;i++) As[c0+i][hr] = w8[i];
    #pragma unroll
    for (int i=0;i<8;i++) Bs[c0+i][hr] = x8[i];
    __syncthreads();
    tile_core(As, Bs, tx, ty, acc);
  }
  #pragma unroll
  for (int j=0;j<4;j++){
    int u = u0 + tx*4 + j;
    if (u < UEN){
      #pragma unroll
      for (int i=0;i<4;i++) op[(size_t)u*ldo + ty*4 + i] = acc[i][j];
    }
  }
}

// ---------------- Xue assemble ----------------
__global__ __launch_bounds__(256) void k_x_ueB(
    const float* __restrict__ T3, const float* __restrict__ T4,
    const float* __restrict__ P3t, const float* __restrict__ R4,
    const int* __restrict__ adj_ue, const int* __restrict__ ue2ue,
    float* __restrict__ Xue)
{
  __shared__ int aj[SS], u2[SS];
  int u = blockIdx.x, t = threadIdx.x;
  if (t < SS){ aj[t] = adj_ue[u*SS+t]; u2[t] = ue2ue[u*SS+t]; }
  __syncthreads();
  int h = t & (H-1);
  float g, s = 0.f;
  if (t < H){
    g = T3[(size_t)u*H + h];
    for (int q=0;q<SS;q++) s += P3t[(size_t)aj[q]*H + h];
  } else {
    g = T4[(size_t)u*H + h];
    for (int q=0;q<SS;q++) s += R4[(size_t)u2[q]*H + h];
  }
  Xue[(size_t)u*H2 + t] = frelu(g + s*INV_NEIGH);
}

// ---------------- X_ap assemble ----------------
__global__ __launch_bounds__(256) void k_x_ap(
    const float* __restrict__ RA, const float* __restrict__ U1,
    const int* __restrict__ adj_ap, const int* __restrict__ ap2ap,
    float* __restrict__ Xap)
{
  __shared__ int aj[SS], a2[SS];
  int i = blockIdx.x, t = threadIdx.x;
  if (t < SS){ aj[t] = adj_ap[i*SS+t]; a2[t] = ap2ap[i*SS+t]; }
  __syncthreads();
  int h = t & (H-1);
  float g, s = 0.f;
  if (t < H){
    g = RA[(size_t)i*H + h];                               // G1
    for (int q=0;q<SS;q++) s += U1[(size_t)aj[q]*H + h];
  } else {
    g = RA[(size_t)APN*H + (size_t)i*H + h];               // G2a
    const float* Q2t = RA + (size_t)2*APN*H;
    for (int q=0;q<SS;q++) s += Q2t[(size_t)a2[q]*H + h];
  }
  Xap[(size_t)i*H2 + t] = frelu(g + s*INV_NEIGH);
}

// ---------------- P7 ----------------
__global__ __launch_bounds__(128) void k_p7(
    const float* __restrict__ Xap, const float* __restrict__ W2ue1,
    float* __restrict__ P7t)
{
  __shared__ float xrow[H2];
  int n = blockIdx.x, t = threadIdx.x;
  xrow[t] = Xap[(size_t)n*H2 + t];
  xrow[t+128] = Xap[(size_t)n*H2 + t + 128];
  __syncthreads();
  const float* w = W2ue1 + (size_t)t*(2*H2) + H2;
  float s0=0.f,s1=0.f,s2=0.f,s3=0.f;
  for (int c=0;c<H2;c+=4){
    s0 = fmaf(w[c  ], xrow[c  ], s0);
    s1 = fmaf(w[c+1], xrow[c+1], s1);
    s2 = fmaf(w[c+2], xrow[c+2], s2);
    s3 = fmaf(w[c+3], xrow[c+3], s3);
  }
  P7t[(size_t)n*H + t] = (s0+s1)+(s2+s3);
}

// ---------------- x7/x8 assemble ----------------
__global__ __launch_bounds__(256) void k_x7x8b(
    float* __restrict__ X2ue, const float* __restrict__ P7t,
    const float* __restrict__ Yb8, const int* __restrict__ adj_ue,
    const int* __restrict__ ue2ue)
{
  __shared__ int aj[SS], u2[SS];
  int u = blockIdx.x, t = threadIdx.x;
  if (t < SS){ aj[t] = adj_ue[u*SS+t]; u2[t] = ue2ue[u*SS+t]; }
  __syncthreads();
  float g = X2ue[(size_t)u*H2 + t];
  float s = 0.f;
  if (t < H){
    for (int q=0;q<SS;q++) s += P7t[(size_t)aj[q]*H + t];
  } else {
    for (int q=0;q<SS;q++) s += Yb8[(size_t)u2[q]*H + (t-H)];
  }
  X2ue[(size_t)u*H2 + t] = frelu(g + s*INV_NEIGH);
}

// ---------------- AP layer 2 + PC head ----------------
__global__ __launch_bounds__(256) void k_ap_layer2_head(
    const float* __restrict__ Xap, const float* __restrict__ Xue,
    const float* __restrict__ W2ap1, const float* __restrict__ W2ap2,
    const int* __restrict__ adj_ap, const int* __restrict__ ap2ap,
    const float* __restrict__ wap1, const float* __restrict__ wap2,
    const float* __restrict__ bais_ap, float* __restrict__ out_pc)
{
  __shared__ float xa[H2], a5[H2], a6[H2], xs2[H2], red[256];
  __shared__ int aj[SS], a2i[SS];
  int i = blockIdx.x, t = threadIdx.x;
  if (t < SS){ aj[t] = adj_ap[i*SS+t]; a2i[t] = ap2ap[i*SS+t]; }
  __syncthreads();
  xa[t] = Xap[(size_t)i*H2+t];
  float s5=0.f, s6=0.f;
  for (int q=0;q<SS;q++){
    s5 += Xue[(size_t)aj[q]*H2 + t];
    s6 += Xap[(size_t)a2i[q]*H2 + t];
  }
  a5[t]=s5*INV_NEIGH; a6[t]=s6*INV_NEIGH;
  __syncthreads();
  const float* w; const float* agg;
  if (t < H){ w = W2ap1 + (size_t)t*(2*H2);     agg = a5; }
  else      { w = W2ap2 + (size_t)(t-H)*(2*H2); agg = a6; }
  float s0=0.f,s1=0.f,s2=0.f,s3=0.f;
  for (int c=0;c<H2;c+=4){
    s0 = fmaf(w[c  ], xa[c  ], s0);
    s1 = fmaf(w[c+1], xa[c+1], s1);
    s2 = fmaf(w[c+2], xa[c+2], s2);
    s3 = fmaf(w[c+3], xa[c+3], s3);
  }
  for (int c=0;c<H2;c+=4){
    s0 = fmaf(w[H2+c  ], agg[c  ], s0);
    s1 = fmaf(w[H2+c+1], agg[c+1], s1);
    s2 = fmaf(w[H2+c+2], agg[c+2], s2);
    s3 = fmaf(w[H2+c+3], agg[c+3], s3);
  }
  xs2[t] = frelu((s0+s1)+(s2+s3));
  __syncthreads();
  float hid = bais_ap[i];
  const float* wr1 = wap1 + (size_t)t*H2;
  for (int c=0;c<H2;c++) hid = fmaf(wr1[c], xs2[c], hid);
  red[t] = wap2[t]*hid;
  __syncthreads();
  for (int o=128;o>0;o>>=1){ if (t<o) red[t]+=red[t+o]; __syncthreads(); }
  if (t==0) out_pc[i] = 1.f/(1.f+expf(-red[0]));
}

// ---------------- BatchNorm ----------------
__global__ __launch_bounds__(256) void k_bn_part(const float* __restrict__ X2ue,
                                                 float* __restrict__ part){
  int b = blockIdx.x, c = threadIdx.x;
  float s=0.f, s2=0.f;
  for (int u = b*125; u < (b+1)*125; u++){
    float v = X2ue[(size_t)u*H2 + c];
    s += v; s2 += v*v;
  }
  part[b*512 + c] = s;
  part[b*512 + 256 + c] = s2;
}

__global__ __launch_bounds__(256) void k_bn_final(
    const float* __restrict__ part, const float* __restrict__ gamma,
    const float* __restrict__ beta, const float* __restrict__ wue,
    float* __restrict__ scsh, float* __restrict__ out_scalar)
{
  __shared__ float red[256];
  int t = threadIdx.x;
  float s=0.f, s2=0.f;
  for (int b=0;b<32;b++){ s += part[b*512+t]; s2 += part[b*512+256+t]; }
  float mean = s*(1.f/UEN);
  float var  = s2*(1.f/UEN) - mean*mean;
  float sc = gamma[t]*rsqrtf(var + 1e-5f);
  scsh[t]    = sc;
  scsh[H2+t] = beta[t] - mean*sc;
  float vsum = 0.f;
  if (t < APN){
    const float* wr = wue + (size_t)t*H2;
    float S=0.f, S2=0.f;
    for (int c=0;c<H2;c++){ float w=wr[c]; S+=w; S2+=w*w; }
    vsum = (S2 - S*S*(1.f/H2)) * (1.f/(H2-1));
  }
  red[t]=vsum; __syncthreads();
  for (int o=128;o>0;o>>=1){ if (t<o) red[t]+=red[t+o]; __syncthreads(); }
  if (t==0) out_scalar[0]=red[0];
}

// ---------------- UA head (BN affine on load) ----------------
__global__ __launch_bounds__(128) void k_ua_head(
    const float* __restrict__ X2ue, const float* __restrict__ scsh,
    const float* __restrict__ wue, const float* __restrict__ bais_ue,
    float* __restrict__ out)
{
  __shared__ float xs[4][H2];
  __shared__ float rmax[128], rmin[128], rs1[128], rs2[128];
  int u0 = blockIdx.x*4, t = threadIdx.x;
  #pragma unroll
  for (int q=0;q<4;q++){
    xs[q][t]     = X2ue[(size_t)(u0+q)*H2 + t]*scsh[t] + scsh[H2+t];
    xs[q][t+128] = X2ue[(size_t)(u0+q)*H2 + t + 128]*scsh[t+128] + scsh[H2+t+128];
  }
  __syncthreads();
  int a = t;
  float acc[4] = {0.f,0.f,0.f,0.f};
  if (a < APN){
    const float* wr = wue + (size_t)a*H2;
    for (int c=0;c<H2;c++){
      float w = wr[c];
      acc[0] = fmaf(w, xs[0][c], acc[0]);
      acc[1] = fmaf(w, xs[1][c], acc[1]);
      acc[2] = fmaf(w, xs[2][c], acc[2]);
      acc[3] = fmaf(w, xs[3][c], acc[3]);
    }
    #pragma unroll
    for (int q=0;q<4;q++) acc[q] += bais_ue[u0+q];
  }
  for (int q=0;q<4;q++){
    rmax[t] = (a<APN) ? acc[q] : -FLT_MAX;
    rmin[t] = (a<APN) ? acc[q] :  FLT_MAX;
    __syncthreads();
    for (int o=64;o>0;o>>=1){
      if (t<o){ rmax[t]=fmaxf(rmax[t],rmax[t+o]); rmin[t]=fminf(rmin[t],rmin[t+o]); }
      __syncthreads();
    }
    float mx = rmax[0], mn = rmin[0];
    __syncthreads();
    float nor = (a<APN) ? (acc[q]-mx)/(mx-mn) : 0.f;
    float e1 = (a<APN) ? expf(nor*1000.f) : 0.f;
    float e2 = (a<APN) ? expf(nor)        : 0.f;
    rs1[t]=e1; rs2[t]=e2;
    __syncthreads();
    for (int o=64;o>0;o>>=1){
      if (t<o){ rs1[t]+=rs1[t+o]; rs2[t]+=rs2[t+o]; }
      __syncthreads();
    }
    float s1=rs1[0], s2=rs2[0];
    __syncthreads();
    if (a<APN){
      size_t u = u0+q;
      out[u*APN + a]                     = acc[q];   // UA_ori
      out[(size_t)UEN*APN   + u*APN + a] = e1/s1;    // UA_de
      out[(size_t)2*UEN*APN + u*APN + a] = e2/s2;    // UA_st
    }
  }
}

extern "C" void kernel_launch(void* const* d_in, const int* in_sizes, int n_in,
                              void* d_out, int out_size, void* d_ws, size_t ws_size,
                              hipStream_t stream) {
  const float* pl      = (const float*)d_in[0];
  const int*   adj_ue  = (const int*)d_in[2];
  const int*   adj_ap  = (const int*)d_in[3];
  const float* W1ap1   = (const float*)d_in[4];
  const float* W1ap2   = (const float*)d_in[5];
  const float* W1ue1   = (const float*)d_in[6];
  const float* W1ue2   = (const float*)d_in[7];
  const float* W2ap1   = (const float*)d_in[8];
  const float* W2ap2   = (const float*)d_in[9];
  const float* W2ue1   = (const float*)d_in[10];
  const float* W2ue2   = (const float*)d_in[11];
  const float* wap1    = (const float*)d_in[12];
  const float* wap2    = (const float*)d_in[13];
  const float* bais_ap = (const float*)d_in[14];
  const float* wue     = (const float*)d_in[15];
  const float* bais_ue = (const float*)d_in[16];
  const float* gamma   = (const float*)d_in[17];
  const float* beta    = (const float*)d_in[18];
  float* out = (float*)d_out;
  (void)in_sizes; (void)n_in; (void)out_size; (void)ws_size;

  char* ws = (char*)d_ws;
  size_t off = 0;
  auto alloc = [&](size_t bytes)->char*{
    char* p = ws + off; off += (bytes + 255) & ~(size_t)255; return p;
  };
  int*   ap2ap = (int*)alloc(APN*SS*4);
  int*   ue2ue = (int*)alloc(UEN*SS*4);
  float* Xap   = (float*)alloc((size_t)APN*H2*4);
  float* Xue   = (float*)alloc((size_t)UEN*H2*4);   // phase1: gemA partials (3.44MB < 4.1MB)
  float* X2ue  = (float*)alloc((size_t)UEN*H2*4);   // phase1: T3|T4
  float* part  = (float*)alloc(32*512*4);
  float* scsh  = (float*)alloc(2*H2*4);
  // ws-buffer aliases (dead-before-write ordering):
  float* partialA = Xue;               // 64*105*128 = 860,160 fl, dead after k_redA
  float* T3 = X2ue;                    // 512,000 fl, dead after k_x_ueB
  float* T4 = X2ue + 512000;           // 512,000 fl, dead after k_x_ueB
  // d_out scratch map (floats; out_size = 1,260,106; all dead before final writes):
  float* U1  = out;                    // 512,000; dead after k_x_ap
  float* Yb8 = out;                    // aliases U1 (k_gemC2 runs after k_x_ap)
  float* R4  = out + 520000;           // 512,000; dead after k_x_ueB
  float* RA  = out + 1040000;          // 4*105*128 (G1,G2a,Q2,P3)
  float* P3t = RA + (size_t)3*APN*H;
  float* P7t = out + 1100000;          // 13,440

  k_twohop        <<<dim3(((APN+UEN)*SS+255)/256), 256, 0, stream>>>(adj_ue, adj_ap, ap2ap, ue2ue);
  k_gemA5         <<<dim3(15,4,NKS), 128, 0, stream>>>(pl, W1ap1, W1ap2, W1ue1, partialA);
  k_redA          <<<dim3((4*APN*H+255)/256), 256, 0, stream>>>(partialA, RA);
  k_gemB2         <<<dim3((UEN+63)/64, 8), 256, 0, stream>>>(pl, W1ap1, W1ue1, W1ue2,
                                                             T3, T4, U1, R4);
  k_x_ueB         <<<dim3(UEN), 256, 0, stream>>>(T3, T4, P3t, R4, adj_ue, ue2ue, Xue);
  k_x_ap          <<<dim3(APN), 256, 0, stream>>>(RA, U1, adj_ap, ap2ap, Xap);
  k_p7            <<<dim3(APN), 128, 0, stream>>>(Xap, W2ue1, P7t);
  k_gemC2         <<<dim3((UEN+63)/64, 6), 256, 0, stream>>>(Xue, W2ue1, W2ue2, X2ue, Yb8);
  k_ap_layer2_head<<<dim3(APN), 256, 0, stream>>>(Xap, Xue, W2ap1, W2ap2, adj_ap, ap2ap,
                                                  wap1, wap2, bais_ap,
                                                  out + (size_t)3*UEN*APN);
  k_x7x8b         <<<dim3(UEN), 256, 0, stream>>>(X2ue, P7t, Yb8, adj_ue, ue2ue);
  k_bn_part       <<<dim3(32), 256, 0, stream>>>(X2ue, part);
  k_bn_final      <<<dim3(1), 256, 0, stream>>>(part, gamma, beta, wue, scsh,
                                                out + (size_t)3*UEN*APN + APN);
  k_ua_head       <<<dim3(UEN/4), 128, 0, stream>>>(X2ue, scsh, wue, bais_ue, out);
}

// Round 12
// 269.818 us; speedup vs baseline: 2.2531x; 1.1852x over previous
//
#include <hip/hip_runtime.h>
#include <math.h>
#include <float.h>

// Round 12: family A rebuilt on the tile_core template (64n x 64h tiles,
// 16-way k-split of 250, coalesced k-major staging). Round-11's k_gemA5 still
// re-read weights 15x (one per n-tile) with per-thread strided rows ->
// 82us latency-bound. Now duplication is 2x and all loads coalesced.
// Everything else identical to round 11 (319us green).

#define APN 105
#define UEN 4000
#define H   128
#define H2  256
#define SS  10
#define INV_NEIGH (1.0f/11.0f)
#define NKS 16
#define KSL 250

__device__ __forceinline__ float frelu(float v){ return v > 0.f ? v : 0.f; }

// ---------------- two-hop indices ----------------
__global__ void k_twohop(const int* __restrict__ adj_ue, const int* __restrict__ adj_ap,
                         int* __restrict__ ap2ap, int* __restrict__ ue2ue){
  int idx = blockIdx.x*256 + threadIdx.x;
  if (idx >= (APN+UEN)*SS) return;
  if (idx < APN*SS){
    int s = idx % SS;
    ap2ap[idx] = adj_ue[adj_ap[idx]*SS + s];
  } else {
    int j = idx - APN*SS;
    int s = j % SS;
    ue2ue[j] = adj_ap[adj_ue[j]*SS + s];
  }
}

// ---------------- tiled GEMM inner core: 32-k chunk, 4x4 micro-tile ----------------
// Scalar LDS reads + capped unroll => bounded register pressure.
__device__ __forceinline__ void tile_core(const float (*As)[68], const float (*Bs)[68],
                                          int tx, int ty, float acc[4][4])
{
  #pragma unroll 4
  for (int k=0;k<32;k++){
    float a0 = As[k][ty*4+0], a1 = As[k][ty*4+1];
    float a2 = As[k][ty*4+2], a3 = As[k][ty*4+3];
    float b0 = Bs[k][tx*4+0], b1 = Bs[k][tx*4+1];
    float b2 = Bs[k][tx*4+2], b3 = Bs[k][tx*4+3];
    acc[0][0]=fmaf(a0,b0,acc[0][0]); acc[0][1]=fmaf(a0,b1,acc[0][1]);
    acc[0][2]=fmaf(a0,b2,acc[0][2]); acc[0][3]=fmaf(a0,b3,acc[0][3]);
    acc[1][0]=fmaf(a1,b0,acc[1][0]); acc[1][1]=fmaf(a1,b1,acc[1][1]);
    acc[1][2]=fmaf(a1,b2,acc[1][2]); acc[1][3]=fmaf(a1,b3,acc[1][3]);
    acc[2][0]=fmaf(a2,b0,acc[2][0]); acc[2][1]=fmaf(a2,b1,acc[2][1]);
    acc[2][2]=fmaf(a2,b2,acc[2][2]); acc[2][3]=fmaf(a2,b3,acc[2][3]);
    acc[3][0]=fmaf(a3,b0,acc[3][0]); acc[3][1]=fmaf(a3,b1,acc[3][1]);
    acc[3][2]=fmaf(a3,b2,acc[3][2]); acc[3][3]=fmaf(a3,b3,acc[3][3]);
  }
}

// ---------------- Family A tiled: grid (2 n-tiles, 8 = slice*2+htile, 16 ks) ----------------
// slice0 G1 = W1ap1[:, :4000]   slice1 G2a = W1ap2[:, :4000]
// slice2 Q2 = W1ap2[:, 4000:]   slice3 P3  = W1ue1[:, 105:]
// partial[(slice*NKS+ks)][n][h] = sum_{k in ks-range} W[h][k]*pl[n][k]
__global__ __launch_bounds__(256) void k_gemA6(
    const float* __restrict__ pl, const float* __restrict__ W1ap1,
    const float* __restrict__ W1ap2, const float* __restrict__ W1ue1,
    float* __restrict__ partial)
{
  __shared__ float As[32][68], Bs[32][68];
  int t = threadIdx.x;
  int n0 = blockIdx.x*64;
  int y = blockIdx.y;              // slice = y>>1, h0 = (y&1)*64
  int ks = blockIdx.z;
  int slice = y>>1, h0 = (y&1)*64, k0 = ks*KSL;
  const float* w; int lda;
  if      (slice == 0){ w = W1ap1;       lda = UEN+APN; }
  else if (slice == 1){ w = W1ap2;       lda = 2*UEN;   }
  else if (slice == 2){ w = W1ap2 + UEN; lda = 2*UEN;   }
  else                { w = W1ue1 + APN; lda = UEN+APN; }
  int tx = t&15, ty = t>>4;
  int hr = t>>2, c0 = (t&3)*8;     // staging: 64 rows x 4 thr, 8 k each
  float acc[4][4] = {};
  for (int kc = 0; kc < 256; kc += 32){
    float w8[8], x8[8];
    const float* wr = w + (size_t)(h0+hr)*lda + k0 + kc + c0;
    #pragma unroll
    for (int i=0;i<8;i++) w8[i] = (kc+c0+i < KSL) ? wr[i] : 0.f;
    const float* xr = pl + (size_t)(n0+hr)*UEN + k0 + kc + c0;
    bool nok = (n0+hr < APN);
    #pragma unroll
    for (int i=0;i<8;i++) x8[i] = (nok && kc+c0+i < KSL) ? xr[i] : 0.f;
    __syncthreads();
    #pragma unroll
    for (int i=0;i<8;i++) As[c0+i][hr] = w8[i];
    #pragma unroll
    for (int i=0;i<8;i++) Bs[c0+i][hr] = x8[i];
    __syncthreads();
    tile_core(As, Bs, tx, ty, acc);
  }
  float* po = partial + (size_t)(slice*NKS+ks)*APN*H;
  #pragma unroll
  for (int j=0;j<4;j++){
    int n = n0 + tx*4 + j;
    if (n < APN){
      #pragma unroll
      for (int i=0;i<4;i++) po[(size_t)n*H + h0 + ty*4 + i] = acc[i][j];
    }
  }
}

__global__ __launch_bounds__(256) void k_redA(const float* __restrict__ partial,
                                              float* __restrict__ RA){
  int idx = blockIdx.x*256 + threadIdx.x;
  if (idx >= 4*APN*H) return;
  int slice = idx / (APN*H), r = idx % (APN*H);
  float s = 0.f;
  #pragma unroll
  for (int ks=0;ks<NKS;ks++) s += partial[((size_t)(slice*NKS+ks)*APN*H) + r];
  RA[idx] = s;
}

// ---------------- Family B tiled: K=105 (padded 128), 4 slices, grid (63, 8) ----------------
__global__ __launch_bounds__(256) void k_gemB2(
    const float* __restrict__ pl, const float* __restrict__ W1ap1,
    const float* __restrict__ W1ue1, const float* __restrict__ W1ue2,
    float* __restrict__ T3, float* __restrict__ T4,
    float* __restrict__ U1, float* __restrict__ R4)
{
  __shared__ float As[32][68], Bs[32][68];
  int t = threadIdx.x, u0 = blockIdx.x*64, y = blockIdx.y;
  int z = y>>1, h0 = (y&1)*64;
  const float* w; int lda; float* op;
  if      (z == 0){ w = W1ue1;       lda = UEN+APN; op = T3; }
  else if (z == 1){ w = W1ue2;       lda = 2*APN;   op = T4; }
  else if (z == 2){ w = W1ap1 + UEN; lda = UEN+APN; op = U1; }
  else            { w = W1ue2 + APN; lda = 2*APN;   op = R4; }
  int tx = t&15, ty = t>>4;
  int hr = t>>2,  c0 = (t&3)*8;
  int kr = t>>3, uu0 = (t&7)*8;
  float acc[4][4] = {};
  for (int kc=0; kc<128; kc+=32){
    float w8[8], x8[8];
    const float* wr = w + (size_t)(h0+hr)*lda + kc + c0;
    #pragma unroll
    for (int i=0;i<8;i++) w8[i] = (kc+c0+i < APN) ? wr[i] : 0.f;
    const float* xr = pl + (size_t)(kc+kr)*UEN + u0 + uu0;
    #pragma unroll
    for (int i=0;i<8;i++)
      x8[i] = (kc+kr < APN && u0+uu0+i < UEN) ? xr[i] : 0.f;
    __syncthreads();
    #pragma unroll
    for (int i=0;i<8;i++) As[c0+i][hr] = w8[i];
    #pragma unroll
    for (int i=0;i<8;i++) Bs[kr][uu0+i] = x8[i];
    __syncthreads();
    tile_core(As, Bs, tx, ty, acc);
  }
  #pragma unroll
  for (int j=0;j<4;j++){
    int u = u0 + tx*4 + j;
    if (u < UEN){
      #pragma unroll
      for (int i=0;i<4;i++) op[(size_t)u*H + h0 + ty*4 + i] = acc[i][j];
    }
  }
}

// ---------------- Family C tiled: K=256, grid (63, 6) ----------------
__global__ __launch_bounds__(256) void k_gemC2(
    const float* __restrict__ Xue, const float* __restrict__ W2ue1,
    const float* __restrict__ W2ue2, float* __restrict__ X2ue,
    float* __restrict__ Yb8)
{
  __shared__ float As[32][68], Bs[32][68];
  int t = threadIdx.x, u0 = blockIdx.x*64, y = blockIdx.y;
  int z = y>>1, h0 = (y&1)*64;
  const float* W = (z == 0) ? W2ue1 : W2ue2;
  int coff = (z == 2) ? H2 : 0;
  float* op; int ldo;
  if      (z == 0){ op = X2ue + h0;     ldo = H2; }
  else if (z == 1){ op = X2ue + H + h0; ldo = H2; }
  else            { op = Yb8 + h0;      ldo = H;  }
  int tx = t&15, ty = t>>4;
  int hr = t>>2, c0 = (t&3)*8;
  float acc[4][4] = {};
  for (int kc=0; kc<H2; kc+=32){
    float w8[8], x8[8];
    const float* wr = W + (size_t)(h0+hr)*(2*H2) + coff + kc + c0;
    #pragma unroll
    for (int i=0;i<8;i++) w8[i] = wr[i];
    const float* xr = Xue + (size_t)(u0+hr)*H2 + kc + c0;
    bool uok = (u0+hr < UEN);
    #pragma unroll
    for (int i=0;i<8;i++) x8[i] = uok ? xr[i] : 0.f;
    __syncthreads();
    #pragma unroll
    for (int i=0;i<8;i++) As[c0+i][hr] = w8[i];
    #pragma unroll
    for (int i=0;i<8;i++) Bs[c0+i][hr] = x8[i];
    __syncthreads();
    tile_core(As, Bs, tx, ty, acc);
  }
  #pragma unroll
  for (int j=0;j<4;j++){
    int u = u0 + tx*4 + j;
    if (u < UEN){
      #pragma unroll
      for (int i=0;i<4;i++) op[(size_t)u*ldo + ty*4 + i] = acc[i][j];
    }
  }
}

// ---------------- Xue assemble ----------------
__global__ __launch_bounds__(256) void k_x_ueB(
    const float* __restrict__ T3, const float* __restrict__ T4,
    const float* __restrict__ P3t, const float* __restrict__ R4,
    const int* __restrict__ adj_ue, const int* __restrict__ ue2ue,
    float* __restrict__ Xue)
{
  __shared__ int aj[SS], u2[SS];
  int u = blockIdx.x, t = threadIdx.x;
  if (t < SS){ aj[t] = adj_ue[u*SS+t]; u2[t] = ue2ue[u*SS+t]; }
  __syncthreads();
  int h = t & (H-1);
  float g, s = 0.f;
  if (t < H){
    g = T3[(size_t)u*H + h];
    for (int q=0;q<SS;q++) s += P3t[(size_t)aj[q]*H + h];
  } else {
    g = T4[(size_t)u*H + h];
    for (int q=0;q<SS;q++) s += R4[(size_t)u2[q]*H + h];
  }
  Xue[(size_t)u*H2 + t] = frelu(g + s*INV_NEIGH);
}

// ---------------- X_ap assemble ----------------
__global__ __launch_bounds__(256) void k_x_ap(
    const float* __restrict__ RA, const float* __restrict__ U1,
    const int* __restrict__ adj_ap, const int* __restrict__ ap2ap,
    float* __restrict__ Xap)
{
  __shared__ int aj[SS], a2[SS];
  int i = blockIdx.x, t = threadIdx.x;
  if (t < SS){ aj[t] = adj_ap[i*SS+t]; a2[t] = ap2ap[i*SS+t]; }
  __syncthreads();
  int h = t & (H-1);
  float g, s = 0.f;
  if (t < H){
    g = RA[(size_t)i*H + h];                               // G1
    for (int q=0;q<SS;q++) s += U1[(size_t)aj[q]*H + h];
  } else {
    g = RA[(size_t)APN*H + (size_t)i*H + h];               // G2a
    const float* Q2t = RA + (size_t)2*APN*H;
    for (int q=0;q<SS;q++) s += Q2t[(size_t)a2[q]*H + h];
  }
  Xap[(size_t)i*H2 + t] = frelu(g + s*INV_NEIGH);
}

// ---------------- P7 ----------------
__global__ __launch_bounds__(128) void k_p7(
    const float* __restrict__ Xap, const float* __restrict__ W2ue1,
    float* __restrict__ P7t)
{
  __shared__ float xrow[H2];
  int n = blockIdx.x, t = threadIdx.x;
  xrow[t] = Xap[(size_t)n*H2 + t];
  xrow[t+128] = Xap[(size_t)n*H2 + t + 128];
  __syncthreads();
  const float* w = W2ue1 + (size_t)t*(2*H2) + H2;
  float s0=0.f,s1=0.f,s2=0.f,s3=0.f;
  for (int c=0;c<H2;c+=4){
    s0 = fmaf(w[c  ], xrow[c  ], s0);
    s1 = fmaf(w[c+1], xrow[c+1], s1);
    s2 = fmaf(w[c+2], xrow[c+2], s2);
    s3 = fmaf(w[c+3], xrow[c+3], s3);
  }
  P7t[(size_t)n*H + t] = (s0+s1)+(s2+s3);
}

// ---------------- x7/x8 assemble ----------------
__global__ __launch_bounds__(256) void k_x7x8b(
    float* __restrict__ X2ue, const float* __restrict__ P7t,
    const float* __restrict__ Yb8, const int* __restrict__ adj_ue,
    const int* __restrict__ ue2ue)
{
  __shared__ int aj[SS], u2[SS];
  int u = blockIdx.x, t = threadIdx.x;
  if (t < SS){ aj[t] = adj_ue[u*SS+t]; u2[t] = ue2ue[u*SS+t]; }
  __syncthreads();
  float g = X2ue[(size_t)u*H2 + t];
  float s = 0.f;
  if (t < H){
    for (int q=0;q<SS;q++) s += P7t[(size_t)aj[q]*H + t];
  } else {
    for (int q=0;q<SS;q++) s += Yb8[(size_t)u2[q]*H + (t-H)];
  }
  X2ue[(size_t)u*H2 + t] = frelu(g + s*INV_NEIGH);
}

// ---------------- AP layer 2 + PC head ----------------
__global__ __launch_bounds__(256) void k_ap_layer2_head(
    const float* __restrict__ Xap, const float* __restrict__ Xue,
    const float* __restrict__ W2ap1, const float* __restrict__ W2ap2,
    const int* __restrict__ adj_ap, const int* __restrict__ ap2ap,
    const float* __restrict__ wap1, const float* __restrict__ wap2,
    const float* __restrict__ bais_ap, float* __restrict__ out_pc)
{
  __shared__ float xa[H2], a5[H2], a6[H2], xs2[H2], red[256];
  __shared__ int aj[SS], a2i[SS];
  int i = blockIdx.x, t = threadIdx.x;
  if (t < SS){ aj[t] = adj_ap[i*SS+t]; a2i[t] = ap2ap[i*SS+t]; }
  __syncthreads();
  xa[t] = Xap[(size_t)i*H2+t];
  float s5=0.f, s6=0.f;
  for (int q=0;q<SS;q++){
    s5 += Xue[(size_t)aj[q]*H2 + t];
    s6 += Xap[(size_t)a2i[q]*H2 + t];
  }
  a5[t]=s5*INV_NEIGH; a6[t]=s6*INV_NEIGH;
  __syncthreads();
  const float* w; const float* agg;
  if (t < H){ w = W2ap1 + (size_t)t*(2*H2);     agg = a5; }
  else      { w = W2ap2 + (size_t)(t-H)*(2*H2); agg = a6; }
  float s0=0.f,s1=0.f,s2=0.f,s3=0.f;
  for (int c=0;c<H2;c+=4){
    s0 = fmaf(w[c  ], xa[c  ], s0);
    s1 = fmaf(w[c+1], xa[c+1], s1);
    s2 = fmaf(w[c+2], xa[c+2], s2);
    s3 = fmaf(w[c+3], xa[c+3], s3);
  }
  for (int c=0;c<H2;c+=4){
    s0 = fmaf(w[H2+c  ], agg[c  ], s0);
    s1 = fmaf(w[H2+c+1], agg[c+1], s1);
    s2 = fmaf(w[H2+c+2], agg[c+2], s2);
    s3 = fmaf(w[H2+c+3], agg[c+3], s3);
  }
  xs2[t] = frelu((s0+s1)+(s2+s3));
  __syncthreads();
  float hid = bais_ap[i];
  const float* wr1 = wap1 + (size_t)t*H2;
  for (int c=0;c<H2;c++) hid = fmaf(wr1[c], xs2[c], hid);
  red[t] = wap2[t]*hid;
  __syncthreads();
  for (int o=128;o>0;o>>=1){ if (t<o) red[t]+=red[t+o]; __syncthreads(); }
  if (t==0) out_pc[i] = 1.f/(1.f+expf(-red[0]));
}

// ---------------- BatchNorm ----------------
__global__ __launch_bounds__(256) void k_bn_part(const float* __restrict__ X2ue,
                                                 float* __restrict__ part){
  int b = blockIdx.x, c = threadIdx.x;
  float s=0.f, s2=0.f;
  for (int u = b*125; u < (b+1)*125; u++){
    float v = X2ue[(size_t)u*H2 + c];
    s += v; s2 += v*v;
  }
  part[b*512 + c] = s;
  part[b*512 + 256 + c] = s2;
}

__global__ __launch_bounds__(256) void k_bn_final(
    const float* __restrict__ part, const float* __restrict__ gamma,
    const float* __restrict__ beta, const float* __restrict__ wue,
    float* __restrict__ scsh, float* __restrict__ out_scalar)
{
  __shared__ float red[256];
  int t = threadIdx.x;
  float s=0.f, s2=0.f;
  for (int b=0;b<32;b++){ s += part[b*512+t]; s2 += part[b*512+256+t]; }
  float mean = s*(1.f/UEN);
  float var  = s2*(1.f/UEN) - mean*mean;
  float sc = gamma[t]*rsqrtf(var + 1e-5f);
  scsh[t]    = sc;
  scsh[H2+t] = beta[t] - mean*sc;
  float vsum = 0.f;
  if (t < APN){
    const float* wr = wue + (size_t)t*H2;
    float S=0.f, S2=0.f;
    for (int c=0;c<H2;c++){ float w=wr[c]; S+=w; S2+=w*w; }
    vsum = (S2 - S*S*(1.f/H2)) * (1.f/(H2-1));
  }
  red[t]=vsum; __syncthreads();
  for (int o=128;o>0;o>>=1){ if (t<o) red[t]+=red[t+o]; __syncthreads(); }
  if (t==0) out_scalar[0]=red[0];
}

// ---------------- UA head (BN affine on load) ----------------
__global__ __launch_bounds__(128) void k_ua_head(
    const float* __restrict__ X2ue, const float* __restrict__ scsh,
    const float* __restrict__ wue, const float* __restrict__ bais_ue,
    float* __restrict__ out)
{
  __shared__ float xs[4][H2];
  __shared__ float rmax[128], rmin[128], rs1[128], rs2[128];
  int u0 = blockIdx.x*4, t = threadIdx.x;
  #pragma unroll
  for (int q=0;q<4;q++){
    xs[q][t]     = X2ue[(size_t)(u0+q)*H2 + t]*scsh[t] + scsh[H2+t];
    xs[q][t+128] = X2ue[(size_t)(u0+q)*H2 + t + 128]*scsh[t+128] + scsh[H2+t+128];
  }
  __syncthreads();
  int a = t;
  float acc[4] = {0.f,0.f,0.f,0.f};
  if (a < APN){
    const float* wr = wue + (size_t)a*H2;
    for (int c=0;c<H2;c++){
      float w = wr[c];
      acc[0] = fmaf(w, xs[0][c], acc[0]);
      acc[1] = fmaf(w, xs[1][c], acc[1]);
      acc[2] = fmaf(w, xs[2][c], acc[2]);
      acc[3] = fmaf(w, xs[3][c], acc[3]);
    }
    #pragma unroll
    for (int q=0;q<4;q++) acc[q] += bais_ue[u0+q];
  }
  for (int q=0;q<4;q++){
    rmax[t] = (a<APN) ? acc[q] : -FLT_MAX;
    rmin[t] = (a<APN) ? acc[q] :  FLT_MAX;
    __syncthreads();
    for (int o=64;o>0;o>>=1){
      if (t<o){ rmax[t]=fmaxf(rmax[t],rmax[t+o]); rmin[t]=fminf(rmin[t],rmin[t+o]); }
      __syncthreads();
    }
    float mx = rmax[0], mn = rmin[0];
    __syncthreads();
    float nor = (a<APN) ? (acc[q]-mx)/(mx-mn) : 0.f;
    float e1 = (a<APN) ? expf(nor*1000.f) : 0.f;
    float e2 = (a<APN) ? expf(nor)        : 0.f;
    rs1[t]=e1; rs2[t]=e2;
    __syncthreads();
    for (int o=64;o>0;o>>=1){
      if (t<o){ rs1[t]+=rs1[t+o]; rs2[t]+=rs2[t+o]; }
      __syncthreads();
    }
    float s1=rs1[0], s2=rs2[0];
    __syncthreads();
    if (a<APN){
      size_t u = u0+q;
      out[u*APN + a]                     = acc[q];   // UA_ori
      out[(size_t)UEN*APN   + u*APN + a] = e1/s1;    // UA_de
      out[(size_t)2*UEN*APN + u*APN + a] = e2/s2;    // UA_st
    }
  }
}

extern "C" void kernel_launch(void* const* d_in, const int* in_sizes, int n_in,
                              void* d_out, int out_size, void* d_ws, size_t ws_size,
                              hipStream_t stream) {
  const float* pl      = (const float*)d_in[0];
  const int*   adj_ue  = (const int*)d_in[2];
  const int*   adj_ap  = (const int*)d_in[3];
  const float* W1ap1   = (const float*)d_in[4];
  const float* W1ap2   = (const float*)d_in[5];
  const float* W1ue1   = (const float*)d_in[6];
  const float* W1ue2   = (const float*)d_in[7];
  const float* W2ap1   = (const float*)d_in[8];
  const float* W2ap2   = (const float*)d_in[9];
  const float* W2ue1   = (const float*)d_in[10];
  const float* W2ue2   = (const float*)d_in[11];
  const float* wap1    = (const float*)d_in[12];
  const float* wap2    = (const float*)d_in[13];
  const float* bais_ap = (const float*)d_in[14];
  const float* wue     = (const float*)d_in[15];
  const float* bais_ue = (const float*)d_in[16];
  const float* gamma   = (const float*)d_in[17];
  const float* beta    = (const float*)d_in[18];
  float* out = (float*)d_out;
  (void)in_sizes; (void)n_in; (void)out_size; (void)ws_size;

  char* ws = (char*)d_ws;
  size_t off = 0;
  auto alloc = [&](size_t bytes)->char*{
    char* p = ws + off; off += (bytes + 255) & ~(size_t)255; return p;
  };
  int*   ap2ap = (int*)alloc(APN*SS*4);
  int*   ue2ue = (int*)alloc(UEN*SS*4);
  float* Xap   = (float*)alloc((size_t)APN*H2*4);
  float* Xue   = (float*)alloc((size_t)UEN*H2*4);   // phase1: gemA partials (3.44MB < 4.1MB)
  float* X2ue  = (float*)alloc((size_t)UEN*H2*4);   // phase1: T3|T4
  float* part  = (float*)alloc(32*512*4);
  float* scsh  = (float*)alloc(2*H2*4);
  // ws-buffer aliases (dead-before-write ordering):
  float* partialA = Xue;               // 64*105*128 = 860,160 fl, dead after k_redA
  float* T3 = X2ue;                    // 512,000 fl, dead after k_x_ueB
  float* T4 = X2ue + 512000;           // 512,000 fl, dead after k_x_ueB
  // d_out scratch map (floats; out_size = 1,260,106; all dead before final writes):
  float* U1  = out;                    // 512,000; dead after k_x_ap
  float* Yb8 = out;                    // aliases U1 (k_gemC2 runs after k_x_ap)
  float* R4  = out + 520000;           // 512,000; dead after k_x_ueB
  float* RA  = out + 1040000;          // 4*105*128 (G1,G2a,Q2,P3)
  float* P3t = RA + (size_t)3*APN*H;
  float* P7t = out + 1100000;          // 13,440

  k_twohop        <<<dim3(((APN+UEN)*SS+255)/256), 256, 0, stream>>>(adj_ue, adj_ap, ap2ap, ue2ue);
  k_gemA6         <<<dim3(2,8,NKS), 256, 0, stream>>>(pl, W1ap1, W1ap2, W1ue1, partialA);
  k_redA          <<<dim3((4*APN*H+255)/256), 256, 0, stream>>>(partialA, RA);
  k_gemB2         <<<dim3((UEN+63)/64, 8), 256, 0, stream>>>(pl, W1ap1, W1ue1, W1ue2,
                                                             T3, T4, U1, R4);
  k_x_ueB         <<<dim3(UEN), 256, 0, stream>>>(T3, T4, P3t, R4, adj_ue, ue2ue, Xue);
  k_x_ap          <<<dim3(APN), 256, 0, stream>>>(RA, U1, adj_ap, ap2ap, Xap);
  k_p7            <<<dim3(APN), 128, 0, stream>>>(Xap, W2ue1, P7t);
  k_gemC2         <<<dim3((UEN+63)/64, 6), 256, 0, stream>>>(Xue, W2ue1, W2ue2, X2ue, Yb8);
  k_ap_layer2_head<<<dim3(APN), 256, 0, stream>>>(Xap, Xue, W2ap1, W2ap2, adj_ap, ap2ap,
                                                  wap1, wap2, bais_ap,
                                                  out + (size_t)3*UEN*APN);
  k_x7x8b         <<<dim3(UEN), 256, 0, stream>>>(X2ue, P7t, Yb8, adj_ue, ue2ue);
  k_bn_part       <<<dim3(32), 256, 0, stream>>>(X2ue, part);
  k_bn_final      <<<dim3(1), 256, 0, stream>>>(part, gamma, beta, wue, scsh,
                                                out + (size_t)3*UEN*APN + APN);
  k_ua_head       <<<dim3(UEN/4), 128, 0, stream>>>(X2ue, scsh, wue, bais_ue, out);
}

// Round 13
// 268.483 us; speedup vs baseline: 2.2643x; 1.0050x over previous
//
#include <hip/hip_runtime.h>
#include <math.h>
#include <float.h>

// Round 13: UA head rework. BN folded into transposed weight (Wue_st[c][a],
// row_off) in k_bn_final2; k_ua_head2 does 8 rows/block with coalesced weight
// reads and shfl-based reductions (2 barriers/row vs 14). bn_part 32->80 blocks.
// GEMMs and plumbing identical to round 12 (270us green). ws_size is 256MB
// (fill dispatches in round-12 profile), so ws budget is a non-issue.

#define APN 105
#define UEN 4000
#define H   128
#define H2  256
#define SS  10
#define INV_NEIGH (1.0f/11.0f)
#define NKS 16
#define KSL 250
#define BNB 80

__device__ __forceinline__ float frelu(float v){ return v > 0.f ? v : 0.f; }

// ---------------- two-hop indices ----------------
__global__ void k_twohop(const int* __restrict__ adj_ue, const int* __restrict__ adj_ap,
                         int* __restrict__ ap2ap, int* __restrict__ ue2ue){
  int idx = blockIdx.x*256 + threadIdx.x;
  if (idx >= (APN+UEN)*SS) return;
  if (idx < APN*SS){
    int s = idx % SS;
    ap2ap[idx] = adj_ue[adj_ap[idx]*SS + s];
  } else {
    int j = idx - APN*SS;
    int s = j % SS;
    ue2ue[j] = adj_ap[adj_ue[j]*SS + s];
  }
}

// ---------------- tiled GEMM inner core: 32-k chunk, 4x4 micro-tile ----------------
__device__ __forceinline__ void tile_core(const float (*As)[68], const float (*Bs)[68],
                                          int tx, int ty, float acc[4][4])
{
  #pragma unroll 4
  for (int k=0;k<32;k++){
    float a0 = As[k][ty*4+0], a1 = As[k][ty*4+1];
    float a2 = As[k][ty*4+2], a3 = As[k][ty*4+3];
    float b0 = Bs[k][tx*4+0], b1 = Bs[k][tx*4+1];
    float b2 = Bs[k][tx*4+2], b3 = Bs[k][tx*4+3];
    acc[0][0]=fmaf(a0,b0,acc[0][0]); acc[0][1]=fmaf(a0,b1,acc[0][1]);
    acc[0][2]=fmaf(a0,b2,acc[0][2]); acc[0][3]=fmaf(a0,b3,acc[0][3]);
    acc[1][0]=fmaf(a1,b0,acc[1][0]); acc[1][1]=fmaf(a1,b1,acc[1][1]);
    acc[1][2]=fmaf(a1,b2,acc[1][2]); acc[1][3]=fmaf(a1,b3,acc[1][3]);
    acc[2][0]=fmaf(a2,b0,acc[2][0]); acc[2][1]=fmaf(a2,b1,acc[2][1]);
    acc[2][2]=fmaf(a2,b2,acc[2][2]); acc[2][3]=fmaf(a2,b3,acc[2][3]);
    acc[3][0]=fmaf(a3,b0,acc[3][0]); acc[3][1]=fmaf(a3,b1,acc[3][1]);
    acc[3][2]=fmaf(a3,b2,acc[3][2]); acc[3][3]=fmaf(a3,b3,acc[3][3]);
  }
}

// ---------------- Family A tiled: grid (2 n-tiles, 8 = slice*2+htile, 16 ks) ----------------
__global__ __launch_bounds__(256) void k_gemA6(
    const float* __restrict__ pl, const float* __restrict__ W1ap1,
    const float* __restrict__ W1ap2, const float* __restrict__ W1ue1,
    float* __restrict__ partial)
{
  __shared__ float As[32][68], Bs[32][68];
  int t = threadIdx.x;
  int n0 = blockIdx.x*64;
  int y = blockIdx.y;
  int ks = blockIdx.z;
  int slice = y>>1, h0 = (y&1)*64, k0 = ks*KSL;
  const float* w; int lda;
  if      (slice == 0){ w = W1ap1;       lda = UEN+APN; }
  else if (slice == 1){ w = W1ap2;       lda = 2*UEN;   }
  else if (slice == 2){ w = W1ap2 + UEN; lda = 2*UEN;   }
  else                { w = W1ue1 + APN; lda = UEN+APN; }
  int tx = t&15, ty = t>>4;
  int hr = t>>2, c0 = (t&3)*8;
  float acc[4][4] = {};
  for (int kc = 0; kc < 256; kc += 32){
    float w8[8], x8[8];
    const float* wr = w + (size_t)(h0+hr)*lda + k0 + kc + c0;
    #pragma unroll
    for (int i=0;i<8;i++) w8[i] = (kc+c0+i < KSL) ? wr[i] : 0.f;
    const float* xr = pl + (size_t)(n0+hr)*UEN + k0 + kc + c0;
    bool nok = (n0+hr < APN);
    #pragma unroll
    for (int i=0;i<8;i++) x8[i] = (nok && kc+c0+i < KSL) ? xr[i] : 0.f;
    __syncthreads();
    #pragma unroll
    for (int i=0;i<8;i++) As[c0+i][hr] = w8[i];
    #pragma unroll
    for (int i=0;i<8;i++) Bs[c0+i][hr] = x8[i];
    __syncthreads();
    tile_core(As, Bs, tx, ty, acc);
  }
  float* po = partial + (size_t)(slice*NKS+ks)*APN*H;
  #pragma unroll
  for (int j=0;j<4;j++){
    int n = n0 + tx*4 + j;
    if (n < APN){
      #pragma unroll
      for (int i=0;i<4;i++) po[(size_t)n*H + h0 + ty*4 + i] = acc[i][j];
    }
  }
}

__global__ __launch_bounds__(256) void k_redA(const float* __restrict__ partial,
                                              float* __restrict__ RA){
  int idx = blockIdx.x*256 + threadIdx.x;
  if (idx >= 4*APN*H) return;
  int slice = idx / (APN*H), r = idx % (APN*H);
  float s = 0.f;
  #pragma unroll
  for (int ks=0;ks<NKS;ks++) s += partial[((size_t)(slice*NKS+ks)*APN*H) + r];
  RA[idx] = s;
}

// ---------------- Family B tiled: K=105 (padded 128), 4 slices, grid (63, 8) ----------------
__global__ __launch_bounds__(256) void k_gemB2(
    const float* __restrict__ pl, const float* __restrict__ W1ap1,
    const float* __restrict__ W1ue1, const float* __restrict__ W1ue2,
    float* __restrict__ T3, float* __restrict__ T4,
    float* __restrict__ U1, float* __restrict__ R4)
{
  __shared__ float As[32][68], Bs[32][68];
  int t = threadIdx.x, u0 = blockIdx.x*64, y = blockIdx.y;
  int z = y>>1, h0 = (y&1)*64;
  const float* w; int lda; float* op;
  if      (z == 0){ w = W1ue1;       lda = UEN+APN; op = T3; }
  else if (z == 1){ w = W1ue2;       lda = 2*APN;   op = T4; }
  else if (z == 2){ w = W1ap1 + UEN; lda = UEN+APN; op = U1; }
  else            { w = W1ue2 + APN; lda = 2*APN;   op = R4; }
  int tx = t&15, ty = t>>4;
  int hr = t>>2,  c0 = (t&3)*8;
  int kr = t>>3, uu0 = (t&7)*8;
  float acc[4][4] = {};
  for (int kc=0; kc<128; kc+=32){
    float w8[8], x8[8];
    const float* wr = w + (size_t)(h0+hr)*lda + kc + c0;
    #pragma unroll
    for (int i=0;i<8;i++) w8[i] = (kc+c0+i < APN) ? wr[i] : 0.f;
    const float* xr = pl + (size_t)(kc+kr)*UEN + u0 + uu0;
    #pragma unroll
    for (int i=0;i<8;i++)
      x8[i] = (kc+kr < APN && u0+uu0+i < UEN) ? xr[i] : 0.f;
    __syncthreads();
    #pragma unroll
    for (int i=0;i<8;i++) As[c0+i][hr] = w8[i];
    #pragma unroll
    for (int i=0;i<8;i++) Bs[kr][uu0+i] = x8[i];
    __syncthreads();
    tile_core(As, Bs, tx, ty, acc);
  }
  #pragma unroll
  for (int j=0;j<4;j++){
    int u = u0 + tx*4 + j;
    if (u < UEN){
      #pragma unroll
      for (int i=0;i<4;i++) op[(size_t)u*H + h0 + ty*4 + i] = acc[i][j];
    }
  }
}

// ---------------- Family C tiled: K=256, grid (63, 6) ----------------
__global__ __launch_bounds__(256) void k_gemC2(
    const float* __restrict__ Xue, const float* __restrict__ W2ue1,
    const float* __restrict__ W2ue2, float* __restrict__ X2ue,
    float* __restrict__ Yb8)
{
  __shared__ float As[32][68], Bs[32][68];
  int t = threadIdx.x, u0 = blockIdx.x*64, y = blockIdx.y;
  int z = y>>1, h0 = (y&1)*64;
  const float* W = (z == 0) ? W2ue1 : W2ue2;
  int coff = (z == 2) ? H2 : 0;
  float* op; int ldo;
  if      (z == 0){ op = X2ue + h0;     ldo = H2; }
  else if (z == 1){ op = X2ue + H + h0; ldo = H2; }
  else            { op = Yb8 + h0;      ldo = H;  }
  int tx = t&15, ty = t>>4;
  int hr = t>>2, c0 = (t&3)*8;
  float acc[4][4] = {};
  for (int kc=0; kc<H2; kc+=32){
    float w8[8], x8[8];
    const float* wr = W + (size_t)(h0+hr)*(2*H2) + coff + kc + c0;
    #pragma unroll
    for (int i=0;i<8;i++) w8[i] = wr[i];
    const float* xr = Xue + (size_t)(u0+hr)*H2 + kc + c0;
    bool uok = (u0+hr < UEN);
    #pragma unroll
    for (int i=0;i<8;i++) x8[i] = uok ? xr[i] : 0.f;
    __syncthreads();
    #pragma unroll
    for (int i=0;i<8;i++) As[c0+i][hr] = w8[i];
    #pragma unroll
    for (int i=0;i<8;i++) Bs[c0+i][hr] = x8[i];
    __syncthreads();
    tile_core(As, Bs, tx, ty, acc);
  }
  #pragma unroll
  for (int j=0;j<4;j++){
    int u = u0 + tx*4 + j;
    if (u < UEN){
      #pragma unroll
      for (int i=0;i<4;i++) op[(size_t)u*ldo + ty*4 + i] = acc[i][j];
    }
  }
}

// ---------------- Xue assemble ----------------
__global__ __launch_bounds__(256) void k_x_ueB(
    const float* __restrict__ T3, const float* __restrict__ T4,
    const float* __restrict__ P3t, const float* __restrict__ R4,
    const int* __restrict__ adj_ue, const int* __restrict__ ue2ue,
    float* __restrict__ Xue)
{
  __shared__ int aj[SS], u2[SS];
  int u = blockIdx.x, t = threadIdx.x;
  if (t < SS){ aj[t] = adj_ue[u*SS+t]; u2[t] = ue2ue[u*SS+t]; }
  __syncthreads();
  int h = t & (H-1);
  float g, s = 0.f;
  if (t < H){
    g = T3[(size_t)u*H + h];
    for (int q=0;q<SS;q++) s += P3t[(size_t)aj[q]*H + h];
  } else {
    g = T4[(size_t)u*H + h];
    for (int q=0;q<SS;q++) s += R4[(size_t)u2[q]*H + h];
  }
  Xue[(size_t)u*H2 + t] = frelu(g + s*INV_NEIGH);
}

// ---------------- X_ap assemble ----------------
__global__ __launch_bounds__(256) void k_x_ap(
    const float* __restrict__ RA, const float* __restrict__ U1,
    const int* __restrict__ adj_ap, const int* __restrict__ ap2ap,
    float* __restrict__ Xap)
{
  __shared__ int aj[SS], a2[SS];
  int i = blockIdx.x, t = threadIdx.x;
  if (t < SS){ aj[t] = adj_ap[i*SS+t]; a2[t] = ap2ap[i*SS+t]; }
  __syncthreads();
  int h = t & (H-1);
  float g, s = 0.f;
  if (t < H){
    g = RA[(size_t)i*H + h];                               // G1
    for (int q=0;q<SS;q++) s += U1[(size_t)aj[q]*H + h];
  } else {
    g = RA[(size_t)APN*H + (size_t)i*H + h];               // G2a
    const float* Q2t = RA + (size_t)2*APN*H;
    for (int q=0;q<SS;q++) s += Q2t[(size_t)a2[q]*H + h];
  }
  Xap[(size_t)i*H2 + t] = frelu(g + s*INV_NEIGH);
}

// ---------------- P7 ----------------
__global__ __launch_bounds__(128) void k_p7(
    const float* __restrict__ Xap, const float* __restrict__ W2ue1,
    float* __restrict__ P7t)
{
  __shared__ float xrow[H2];
  int n = blockIdx.x, t = threadIdx.x;
  xrow[t] = Xap[(size_t)n*H2 + t];
  xrow[t+128] = Xap[(size_t)n*H2 + t + 128];
  __syncthreads();
  const float* w = W2ue1 + (size_t)t*(2*H2) + H2;
  float s0=0.f,s1=0.f,s2=0.f,s3=0.f;
  for (int c=0;c<H2;c+=4){
    s0 = fmaf(w[c  ], xrow[c  ], s0);
    s1 = fmaf(w[c+1], xrow[c+1], s1);
    s2 = fmaf(w[c+2], xrow[c+2], s2);
    s3 = fmaf(w[c+3], xrow[c+3], s3);
  }
  P7t[(size_t)n*H + t] = (s0+s1)+(s2+s3);
}

// ---------------- x7/x8 assemble ----------------
__global__ __launch_bounds__(256) void k_x7x8b(
    float* __restrict__ X2ue, const float* __restrict__ P7t,
    const float* __restrict__ Yb8, const int* __restrict__ adj_ue,
    const int* __restrict__ ue2ue)
{
  __shared__ int aj[SS], u2[SS];
  int u = blockIdx.x, t = threadIdx.x;
  if (t < SS){ aj[t] = adj_ue[u*SS+t]; u2[t] = ue2ue[u*SS+t]; }
  __syncthreads();
  float g = X2ue[(size_t)u*H2 + t];
  float s = 0.f;
  if (t < H){
    for (int q=0;q<SS;q++) s += P7t[(size_t)aj[q]*H + t];
  } else {
    for (int q=0;q<SS;q++) s += Yb8[(size_t)u2[q]*H + (t-H)];
  }
  X2ue[(size_t)u*H2 + t] = frelu(g + s*INV_NEIGH);
}

// ---------------- AP layer 2 + PC head ----------------
__global__ __launch_bounds__(256) void k_ap_layer2_head(
    const float* __restrict__ Xap, const float* __restrict__ Xue,
    const float* __restrict__ W2ap1, const float* __restrict__ W2ap2,
    const int* __restrict__ adj_ap, const int* __restrict__ ap2ap,
    const float* __restrict__ wap1, const float* __restrict__ wap2,
    const float* __restrict__ bais_ap, float* __restrict__ out_pc)
{
  __shared__ float xa[H2], a5[H2], a6[H2], xs2[H2], red[256];
  __shared__ int aj[SS], a2i[SS];
  int i = blockIdx.x, t = threadIdx.x;
  if (t < SS){ aj[t] = adj_ap[i*SS+t]; a2i[t] = ap2ap[i*SS+t]; }
  __syncthreads();
  xa[t] = Xap[(size_t)i*H2+t];
  float s5=0.f, s6=0.f;
  for (int q=0;q<SS;q++){
    s5 += Xue[(size_t)aj[q]*H2 + t];
    s6 += Xap[(size_t)a2i[q]*H2 + t];
  }
  a5[t]=s5*INV_NEIGH; a6[t]=s6*INV_NEIGH;
  __syncthreads();
  const float* w; const float* agg;
  if (t < H){ w = W2ap1 + (size_t)t*(2*H2);     agg = a5; }
  else      { w = W2ap2 + (size_t)(t-H)*(2*H2); agg = a6; }
  float s0=0.f,s1=0.f,s2=0.f,s3=0.f;
  for (int c=0;c<H2;c+=4){
    s0 = fmaf(w[c  ], xa[c  ], s0);
    s1 = fmaf(w[c+1], xa[c+1], s1);
    s2 = fmaf(w[c+2], xa[c+2], s2);
    s3 = fmaf(w[c+3], xa[c+3], s3);
  }
  for (int c=0;c<H2;c+=4){
    s0 = fmaf(w[H2+c  ], agg[c  ], s0);
    s1 = fmaf(w[H2+c+1], agg[c+1], s1);
    s2 = fmaf(w[H2+c+2], agg[c+2], s2);
    s3 = fmaf(w[H2+c+3], agg[c+3], s3);
  }
  xs2[t] = frelu((s0+s1)+(s2+s3));
  __syncthreads();
  float hid = bais_ap[i];
  const float* wr1 = wap1 + (size_t)t*H2;
  for (int c=0;c<H2;c++) hid = fmaf(wr1[c], xs2[c], hid);
  red[t] = wap2[t]*hid;
  __syncthreads();
  for (int o=128;o>0;o>>=1){ if (t<o) red[t]+=red[t+o]; __syncthreads(); }
  if (t==0) out_pc[i] = 1.f/(1.f+expf(-red[0]));
}

// ---------------- BatchNorm stats: 80 blocks x 50 rows ----------------
__global__ __launch_bounds__(256) void k_bn_part(const float* __restrict__ X2ue,
                                                 float* __restrict__ part){
  int b = blockIdx.x, c = threadIdx.x;
  float s=0.f, s2=0.f;
  for (int u = b*50; u < (b+1)*50; u++){
    float v = X2ue[(size_t)u*H2 + c];
    s += v; s2 += v*v;
  }
  part[b*512 + c] = s;
  part[b*512 + 256 + c] = s2;
}

// ---------------- BN finalize: fold affine into transposed weight + row offsets ----------------
__global__ __launch_bounds__(256) void k_bn_final2(
    const float* __restrict__ part, const float* __restrict__ gamma,
    const float* __restrict__ beta, const float* __restrict__ wue,
    float* __restrict__ Wue_st, float* __restrict__ row_off,
    float* __restrict__ out_scalar)
{
  __shared__ float shs[H2], red[256];
  int t = threadIdx.x;
  float s=0.f, s2=0.f;
  for (int b=0;b<BNB;b++){ s += part[b*512+t]; s2 += part[b*512+256+t]; }
  float mean = s*(1.f/UEN);
  float var  = s2*(1.f/UEN) - mean*mean;       // biased, training-mode BN
  float sc = gamma[t]*rsqrtf(var + 1e-5f);
  shs[t] = beta[t] - mean*sc;
  // Wue_st[c][a] = wue[a][c] * sc[c]; reads coalesced across lanes (fixed a)
  for (int a=0;a<APN;a++)
    Wue_st[(size_t)t*APN + a] = wue[(size_t)a*H2 + t]*sc;
  __syncthreads();
  float vsum = 0.f;
  if (t < APN){
    const float* wr = wue + (size_t)t*H2;
    float ro=0.f, S=0.f, S2=0.f;
    for (int c=0;c<H2;c++){
      float w = wr[c];
      ro = fmaf(w, shs[c], ro);
      S += w; S2 += w*w;
    }
    row_off[t] = ro;
    vsum = (S2 - S*S*(1.f/H2)) * (1.f/(H2-1));  // ddof=1
  }
  red[t]=vsum; __syncthreads();
  for (int o=128;o>0;o>>=1){ if (t<o) red[t]+=red[t+o]; __syncthreads(); }
  if (t==0) out_scalar[0]=red[0];
}

// ---------------- UA head v2: 8 rows/block, coalesced folded weight, shfl reductions ----------------
__global__ __launch_bounds__(128) void k_ua_head2(
    const float* __restrict__ X2ue, const float* __restrict__ Wue_st,
    const float* __restrict__ row_off, const float* __restrict__ bais_ue,
    float* __restrict__ out)
{
  __shared__ float xs[8][H2];
  __shared__ float wmax[2], wmin[2], ws1[2], ws2[2];
  int u0 = blockIdx.x*8, t = threadIdx.x;
  #pragma unroll
  for (int q=0;q<8;q++){
    xs[q][t]     = X2ue[(size_t)(u0+q)*H2 + t];
    xs[q][t+128] = X2ue[(size_t)(u0+q)*H2 + t + 128];
  }
  __syncthreads();
  int a = t;                                   // lanes 0..104 active
  float acc[8];
  #pragma unroll
  for (int q=0;q<8;q++) acc[q] = 0.f;
  if (a < APN){
    float ro = row_off[a];
    #pragma unroll
    for (int q=0;q<8;q++) acc[q] = ro + bais_ue[u0+q];
    for (int c=0;c<H2;c++){
      float w = Wue_st[(size_t)c*APN + a];     // coalesced across lanes
      #pragma unroll
      for (int q=0;q<8;q++) acc[q] = fmaf(w, xs[q][c], acc[q]);
    }
  }
  int wid = t>>6;
  for (int q=0;q<8;q++){
    float vmax = (a<APN) ? acc[q] : -FLT_MAX;
    float vmin = (a<APN) ? acc[q] :  FLT_MAX;
    #pragma unroll
    for (int o=32;o>0;o>>=1){
      vmax = fmaxf(vmax, __shfl_xor(vmax, o));
      vmin = fminf(vmin, __shfl_xor(vmin, o));
    }
    if ((t&63)==0){ wmax[wid]=vmax; wmin[wid]=vmin; }
    __syncthreads();
    float mx = fmaxf(wmax[0], wmax[1]);
    float mn = fminf(wmin[0], wmin[1]);
    float nor = (a<APN) ? (acc[q]-mx)/(mx-mn) : 0.f;   // in [-1,0]
    float e1 = (a<APN) ? expf(nor*1000.f) : 0.f;
    float e2 = (a<APN) ? expf(nor)        : 0.f;
    float s1 = e1, s2 = e2;
    #pragma unroll
    for (int o=32;o>0;o>>=1){
      s1 += __shfl_xor(s1, o);
      s2 += __shfl_xor(s2, o);
    }
    if ((t&63)==0){ ws1[wid]=s1; ws2[wid]=s2; }
    __syncthreads();
    float S1 = ws1[0]+ws1[1], S2 = ws2[0]+ws2[1];
    if (a < APN){
      size_t u = u0+q;
      out[u*APN + a]                     = acc[q];   // UA_ori
      out[(size_t)UEN*APN   + u*APN + a] = e1/S1;    // UA_de
      out[(size_t)2*UEN*APN + u*APN + a] = e2/S2;    // UA_st
    }
  }
}

extern "C" void kernel_launch(void* const* d_in, const int* in_sizes, int n_in,
                              void* d_out, int out_size, void* d_ws, size_t ws_size,
                              hipStream_t stream) {
  const float* pl      = (const float*)d_in[0];
  const int*   adj_ue  = (const int*)d_in[2];
  const int*   adj_ap  = (const int*)d_in[3];
  const float* W1ap1   = (const float*)d_in[4];
  const float* W1ap2   = (const float*)d_in[5];
  const float* W1ue1   = (const float*)d_in[6];
  const float* W1ue2   = (const float*)d_in[7];
  const float* W2ap1   = (const float*)d_in[8];
  const float* W2ap2   = (const float*)d_in[9];
  const float* W2ue1   = (const float*)d_in[10];
  const float* W2ue2   = (const float*)d_in[11];
  const float* wap1    = (const float*)d_in[12];
  const float* wap2    = (const float*)d_in[13];
  const float* bais_ap = (const float*)d_in[14];
  const float* wue     = (const float*)d_in[15];
  const float* bais_ue = (const float*)d_in[16];
  const float* gamma   = (const float*)d_in[17];
  const float* beta    = (const float*)d_in[18];
  float* out = (float*)d_out;
  (void)in_sizes; (void)n_in; (void)out_size; (void)ws_size;

  char* ws = (char*)d_ws;
  size_t off = 0;
  auto alloc = [&](size_t bytes)->char*{
    char* p = ws + off; off += (bytes + 255) & ~(size_t)255; return p;
  };
  int*   ap2ap  = (int*)alloc(APN*SS*4);
  int*   ue2ue  = (int*)alloc(UEN*SS*4);
  float* Xap    = (float*)alloc((size_t)APN*H2*4);
  float* Xue    = (float*)alloc((size_t)UEN*H2*4);   // phase1: gemA partials
  float* X2ue   = (float*)alloc((size_t)UEN*H2*4);   // phase1: T3|T4
  float* part   = (float*)alloc((size_t)BNB*512*4);
  float* Wue_st = (float*)alloc((size_t)H2*APN*4);
  float* rowoff = (float*)alloc(APN*4);
  // ws-buffer aliases (dead-before-write ordering):
  float* partialA = Xue;               // 64*105*128 fl, dead after k_redA
  float* T3 = X2ue;                    // dead after k_x_ueB
  float* T4 = X2ue + 512000;           // dead after k_x_ueB
  // d_out scratch map (floats; out_size = 1,260,106; all dead before final writes):
  float* U1  = out;                    // dead after k_x_ap
  float* Yb8 = out;                    // aliases U1 (k_gemC2 runs after k_x_ap)
  float* R4  = out + 520000;           // dead after k_x_ueB
  float* RA  = out + 1040000;          // 4*105*128 (G1,G2a,Q2,P3)
  float* P3t = RA + (size_t)3*APN*H;
  float* P7t = out + 1100000;

  k_twohop        <<<dim3(((APN+UEN)*SS+255)/256), 256, 0, stream>>>(adj_ue, adj_ap, ap2ap, ue2ue);
  k_gemA6         <<<dim3(2,8,NKS), 256, 0, stream>>>(pl, W1ap1, W1ap2, W1ue1, partialA);
  k_redA          <<<dim3((4*APN*H+255)/256), 256, 0, stream>>>(partialA, RA);
  k_gemB2         <<<dim3((UEN+63)/64, 8), 256, 0, stream>>>(pl, W1ap1, W1ue1, W1ue2,
                                                             T3, T4, U1, R4);
  k_x_ueB         <<<dim3(UEN), 256, 0, stream>>>(T3, T4, P3t, R4, adj_ue, ue2ue, Xue);
  k_x_ap          <<<dim3(APN), 256, 0, stream>>>(RA, U1, adj_ap, ap2ap, Xap);
  k_p7            <<<dim3(APN), 128, 0, stream>>>(Xap, W2ue1, P7t);
  k_gemC2         <<<dim3((UEN+63)/64, 6), 256, 0, stream>>>(Xue, W2ue1, W2ue2, X2ue, Yb8);
  k_ap_layer2_head<<<dim3(APN), 256, 0, stream>>>(Xap, Xue, W2ap1, W2ap2, adj_ap, ap2ap,
                                                  wap1, wap2, bais_ap,
                                                  out + (size_t)3*UEN*APN);
  k_x7x8b         <<<dim3(UEN), 256, 0, stream>>>(X2ue, P7t, Yb8, adj_ue, ue2ue);
  k_bn_part       <<<dim3(BNB), 256, 0, stream>>>(X2ue, part);
  k_bn_final2     <<<dim3(1), 256, 0, stream>>>(part, gamma, beta, wue, Wue_st, rowoff,
                                                out + (size_t)3*UEN*APN + APN);
  k_ua_head2      <<<dim3(UEN/8), 128, 0, stream>>>(X2ue, Wue_st, rowoff, bais_ue, out);
}

// Round 14
// 220.191 us; speedup vs baseline: 2.7609x; 1.2193x over previous
//
#include <hip/hip_runtime.h>
#include <math.h>
#include <float.h>

// Round 14: launch-count reduction 13 -> 7 by fusing independent stages:
//  k_front = twohop || gemA6 || gemB2 || var_ue   (922 blocks)
//  k_redA                                          (210)
//  k_mid1  = x_ueB || x_ap                         (4105)
//  k_mid2  = gemC2 || p7 || ap_layer2_head         (588)
//  k_x7x8b                                         (4000)
//  k_bn_part                                       (80)
//  k_ua_head3 (BN scale/shift computed per-block; bn_final kernel deleted)
// All per-path math verbatim from green round 13 (268us).

#define APN 105
#define UEN 4000
#define H   128
#define H2  256
#define SS  10
#define INV_NEIGH (1.0f/11.0f)
#define NKS 16
#define KSL 250
#define BNB 80

#define NB_A 256           // gemA6 blocks
#define NB_B 504           // gemB2 blocks
#define NB_T 161           // twohop blocks
#define NB_FRONT (NB_A+NB_B+NB_T+1)

__device__ __forceinline__ float frelu(float v){ return v > 0.f ? v : 0.f; }

// ---------------- tiled GEMM inner core: 32-k chunk, 4x4 micro-tile ----------------
__device__ __forceinline__ void tile_core(const float (*As)[68], const float (*Bs)[68],
                                          int tx, int ty, float acc[4][4])
{
  #pragma unroll 4
  for (int k=0;k<32;k++){
    float a0 = As[k][ty*4+0], a1 = As[k][ty*4+1];
    float a2 = As[k][ty*4+2], a3 = As[k][ty*4+3];
    float b0 = Bs[k][tx*4+0], b1 = Bs[k][tx*4+1];
    float b2 = Bs[k][tx*4+2], b3 = Bs[k][tx*4+3];
    acc[0][0]=fmaf(a0,b0,acc[0][0]); acc[0][1]=fmaf(a0,b1,acc[0][1]);
    acc[0][2]=fmaf(a0,b2,acc[0][2]); acc[0][3]=fmaf(a0,b3,acc[0][3]);
    acc[1][0]=fmaf(a1,b0,acc[1][0]); acc[1][1]=fmaf(a1,b1,acc[1][1]);
    acc[1][2]=fmaf(a1,b2,acc[1][2]); acc[1][3]=fmaf(a1,b3,acc[1][3]);
    acc[2][0]=fmaf(a2,b0,acc[2][0]); acc[2][1]=fmaf(a2,b1,acc[2][1]);
    acc[2][2]=fmaf(a2,b2,acc[2][2]); acc[2][3]=fmaf(a2,b3,acc[2][3]);
    acc[3][0]=fmaf(a3,b0,acc[3][0]); acc[3][1]=fmaf(a3,b1,acc[3][1]);
    acc[3][2]=fmaf(a3,b2,acc[3][2]); acc[3][3]=fmaf(a3,b3,acc[3][3]);
  }
}

// ---------------- launch 1: twohop || gemA6 || gemB2 || var_ue ----------------
__global__ __launch_bounds__(256) void k_front(
    const float* __restrict__ pl, const float* __restrict__ W1ap1,
    const float* __restrict__ W1ap2, const float* __restrict__ W1ue1,
    const float* __restrict__ W1ue2,
    const int* __restrict__ adj_ue, const int* __restrict__ adj_ap,
    int* __restrict__ ap2ap, int* __restrict__ ue2ue,
    float* __restrict__ partial,
    float* __restrict__ T3, float* __restrict__ T4,
    float* __restrict__ U1, float* __restrict__ R4,
    const float* __restrict__ wue, float* __restrict__ out_scalar)
{
  __shared__ float As[32][68], Bs[32][68];
  __shared__ float red[256];
  int b = blockIdx.x, t = threadIdx.x;

  if (b < NB_A){
    // ---- gemA6: slices G1,G2a,Q2,P3 over K=4000, 16-way k-split ----
    int nt = b & 1, y = (b>>1) & 7, ks = b >> 4;
    int n0 = nt*64, slice = y>>1, h0 = (y&1)*64, k0 = ks*KSL;
    const float* w; int lda;
    if      (slice == 0){ w = W1ap1;       lda = UEN+APN; }
    else if (slice == 1){ w = W1ap2;       lda = 2*UEN;   }
    else if (slice == 2){ w = W1ap2 + UEN; lda = 2*UEN;   }
    else                { w = W1ue1 + APN; lda = UEN+APN; }
    int tx = t&15, ty = t>>4;
    int hr = t>>2, c0 = (t&3)*8;
    float acc[4][4] = {};
    for (int kc = 0; kc < 256; kc += 32){
      float w8[8], x8[8];
      const float* wr = w + (size_t)(h0+hr)*lda + k0 + kc + c0;
      #pragma unroll
      for (int i=0;i<8;i++) w8[i] = (kc+c0+i < KSL) ? wr[i] : 0.f;
      const float* xr = pl + (size_t)(n0+hr)*UEN + k0 + kc + c0;
      bool nok = (n0+hr < APN);
      #pragma unroll
      for (int i=0;i<8;i++) x8[i] = (nok && kc+c0+i < KSL) ? xr[i] : 0.f;
      __syncthreads();
      #pragma unroll
      for (int i=0;i<8;i++) As[c0+i][hr] = w8[i];
      #pragma unroll
      for (int i=0;i<8;i++) Bs[c0+i][hr] = x8[i];
      __syncthreads();
      tile_core(As, Bs, tx, ty, acc);
    }
    float* po = partial + (size_t)(slice*NKS+ks)*APN*H;
    #pragma unroll
    for (int j=0;j<4;j++){
      int n = n0 + tx*4 + j;
      if (n < APN){
        #pragma unroll
        for (int i=0;i<4;i++) po[(size_t)n*H + h0 + ty*4 + i] = acc[i][j];
      }
    }
  } else if (b < NB_A + NB_B){
    // ---- gemB2: T3,T4,U1,R4 over K=105 (padded 128) ----
    int c = b - NB_A;
    int u0 = (c % 63)*64, y = c / 63;
    int z = y>>1, h0 = (y&1)*64;
    const float* w; int lda; float* op;
    if      (z == 0){ w = W1ue1;       lda = UEN+APN; op = T3; }
    else if (z == 1){ w = W1ue2;       lda = 2*APN;   op = T4; }
    else if (z == 2){ w = W1ap1 + UEN; lda = UEN+APN; op = U1; }
    else            { w = W1ue2 + APN; lda = 2*APN;   op = R4; }
    int tx = t&15, ty = t>>4;
    int hr = t>>2,  c0 = (t&3)*8;
    int kr = t>>3, uu0 = (t&7)*8;
    float acc[4][4] = {};
    for (int kc=0; kc<128; kc+=32){
      float w8[8], x8[8];
      const float* wr = w + (size_t)(h0+hr)*lda + kc + c0;
      #pragma unroll
      for (int i=0;i<8;i++) w8[i] = (kc+c0+i < APN) ? wr[i] : 0.f;
      const float* xr = pl + (size_t)(kc+kr)*UEN + u0 + uu0;
      #pragma unroll
      for (int i=0;i<8;i++)
        x8[i] = (kc+kr < APN && u0+uu0+i < UEN) ? xr[i] : 0.f;
      __syncthreads();
      #pragma unroll
      for (int i=0;i<8;i++) As[c0+i][hr] = w8[i];
      #pragma unroll
      for (int i=0;i<8;i++) Bs[kr][uu0+i] = x8[i];
      __syncthreads();
      tile_core(As, Bs, tx, ty, acc);
    }
    #pragma unroll
    for (int j=0;j<4;j++){
      int u = u0 + tx*4 + j;
      if (u < UEN){
        #pragma unroll
        for (int i=0;i<4;i++) op[(size_t)u*H + h0 + ty*4 + i] = acc[i][j];
      }
    }
  } else if (b < NB_A + NB_B + NB_T){
    // ---- twohop indices ----
    int idx = (b - NB_A - NB_B)*256 + t;
    if (idx < (APN+UEN)*SS){
      if (idx < APN*SS){
        int s = idx % SS;
        ap2ap[idx] = adj_ue[adj_ap[idx]*SS + s];
      } else {
        int j = idx - APN*SS;
        int s = j % SS;
        ue2ue[j] = adj_ap[adj_ue[j]*SS + s];
      }
    }
  } else {
    // ---- var_ue scalar: sum over rows of unbiased var of wue ----
    float vsum = 0.f;
    if (t < APN){
      const float* wr = wue + (size_t)t*H2;
      float S=0.f, S2=0.f;
      for (int c=0;c<H2;c++){ float w=wr[c]; S+=w; S2+=w*w; }
      vsum = (S2 - S*S*(1.f/H2)) * (1.f/(H2-1));   // ddof=1
    }
    red[t]=vsum; __syncthreads();
    for (int o=128;o>0;o>>=1){ if (t<o) red[t]+=red[t+o]; __syncthreads(); }
    if (t==0) out_scalar[0]=red[0];
  }
}

// ---------------- launch 2: redA ----------------
__global__ __launch_bounds__(256) void k_redA(const float* __restrict__ partial,
                                              float* __restrict__ RA){
  int idx = blockIdx.x*256 + threadIdx.x;
  if (idx >= 4*APN*H) return;
  int slice = idx / (APN*H), r = idx % (APN*H);
  float s = 0.f;
  #pragma unroll
  for (int ks=0;ks<NKS;ks++) s += partial[((size_t)(slice*NKS+ks)*APN*H) + r];
  RA[idx] = s;
}

// ---------------- launch 3: x_ueB || x_ap ----------------
__global__ __launch_bounds__(256) void k_mid1(
    const float* __restrict__ T3, const float* __restrict__ T4,
    const float* __restrict__ P3t, const float* __restrict__ R4,
    const float* __restrict__ RA, const float* __restrict__ U1,
    const int* __restrict__ adj_ue, const int* __restrict__ ue2ue,
    const int* __restrict__ adj_ap, const int* __restrict__ ap2ap,
    float* __restrict__ Xue, float* __restrict__ Xap)
{
  __shared__ int aj[SS], b2[SS];
  int b = blockIdx.x, t = threadIdx.x;
  int h = t & (H-1);
  if (b < UEN){
    int u = b;
    if (t < SS){ aj[t] = adj_ue[u*SS+t]; b2[t] = ue2ue[u*SS+t]; }
    __syncthreads();
    float g, s = 0.f;
    if (t < H){
      g = T3[(size_t)u*H + h];
      for (int q=0;q<SS;q++) s += P3t[(size_t)aj[q]*H + h];
    } else {
      g = T4[(size_t)u*H + h];
      for (int q=0;q<SS;q++) s += R4[(size_t)b2[q]*H + h];
    }
    Xue[(size_t)u*H2 + t] = frelu(g + s*INV_NEIGH);
  } else {
    int i = b - UEN;
    if (t < SS){ aj[t] = adj_ap[i*SS+t]; b2[t] = ap2ap[i*SS+t]; }
    __syncthreads();
    float g, s = 0.f;
    if (t < H){
      g = RA[(size_t)i*H + h];                               // G1
      for (int q=0;q<SS;q++) s += U1[(size_t)aj[q]*H + h];
    } else {
      g = RA[(size_t)APN*H + (size_t)i*H + h];               // G2a
      const float* Q2t = RA + (size_t)2*APN*H;
      for (int q=0;q<SS;q++) s += Q2t[(size_t)b2[q]*H + h];
    }
    Xap[(size_t)i*H2 + t] = frelu(g + s*INV_NEIGH);
  }
}

// ---------------- launch 4: gemC2 || p7 || ap_layer2_head ----------------
__global__ __launch_bounds__(256) void k_mid2(
    const float* __restrict__ Xue, const float* __restrict__ Xap,
    const float* __restrict__ W2ue1, const float* __restrict__ W2ue2,
    const float* __restrict__ W2ap1, const float* __restrict__ W2ap2,
    const int* __restrict__ adj_ap, const int* __restrict__ ap2ap,
    const float* __restrict__ wap1, const float* __restrict__ wap2,
    const float* __restrict__ bais_ap,
    float* __restrict__ X2ue, float* __restrict__ Yb8,
    float* __restrict__ P7t, float* __restrict__ out_pc)
{
  __shared__ float As[32][68], Bs[32][68];
  __shared__ float xa[H2], a5[H2], a6[H2], xs2[H2], red[256];
  __shared__ int aj[SS], a2i[SS];
  int b = blockIdx.x, t = threadIdx.x;

  if (b < 378){
    // ---- gemC2 ----
    int u0 = (b % 63)*64, y = b / 63;
    int z = y>>1, h0 = (y&1)*64;
    const float* W = (z == 0) ? W2ue1 : W2ue2;
    int coff = (z == 2) ? H2 : 0;
    float* op; int ldo;
    if      (z == 0){ op = X2ue + h0;     ldo = H2; }
    else if (z == 1){ op = X2ue + H + h0; ldo = H2; }
    else            { op = Yb8 + h0;      ldo = H;  }
    int tx = t&15, ty = t>>4;
    int hr = t>>2, c0 = (t&3)*8;
    float acc[4][4] = {};
    for (int kc=0; kc<H2; kc+=32){
      float w8[8], x8[8];
      const float* wr = W + (size_t)(h0+hr)*(2*H2) + coff + kc + c0;
      #pragma unroll
      for (int i=0;i<8;i++) w8[i] = wr[i];
      const float* xr = Xue + (size_t)(u0+hr)*H2 + kc + c0;
      bool uok = (u0+hr < UEN);
      #pragma unroll
      for (int i=0;i<8;i++) x8[i] = uok ? xr[i] : 0.f;
      __syncthreads();
      #pragma unroll
      for (int i=0;i<8;i++) As[c0+i][hr] = w8[i];
      #pragma unroll
      for (int i=0;i<8;i++) Bs[c0+i][hr] = x8[i];
      __syncthreads();
      tile_core(As, Bs, tx, ty, acc);
    }
    #pragma unroll
    for (int j=0;j<4;j++){
      int u = u0 + tx*4 + j;
      if (u < UEN){
        #pragma unroll
        for (int i=0;i<4;i++) op[(size_t)u*ldo + ty*4 + i] = acc[i][j];
      }
    }
  } else if (b < 483){
    // ---- p7: P7t[n][h] = sum_c W2ue1[h, H2+c]*Xap[n, c] ----
    int n = b - 378;
    xa[t] = Xap[(size_t)n*H2 + t];          // reuse xa as xrow[256]
    __syncthreads();
    if (t < H){
      const float* w = W2ue1 + (size_t)t*(2*H2) + H2;
      float s0=0.f,s1=0.f,s2=0.f,s3=0.f;
      for (int c=0;c<H2;c+=4){
        s0 = fmaf(w[c  ], xa[c  ], s0);
        s1 = fmaf(w[c+1], xa[c+1], s1);
        s2 = fmaf(w[c+2], xa[c+2], s2);
        s3 = fmaf(w[c+3], xa[c+3], s3);
      }
      P7t[(size_t)n*H + t] = (s0+s1)+(s2+s3);
    }
  } else {
    // ---- ap_layer2_head ----
    int i = b - 483;
    if (t < SS){ aj[t] = adj_ap[i*SS+t]; a2i[t] = ap2ap[i*SS+t]; }
    __syncthreads();
    xa[t] = Xap[(size_t)i*H2+t];
    float s5=0.f, s6=0.f;
    for (int q=0;q<SS;q++){
      s5 += Xue[(size_t)aj[q]*H2 + t];
      s6 += Xap[(size_t)a2i[q]*H2 + t];
    }
    a5[t]=s5*INV_NEIGH; a6[t]=s6*INV_NEIGH;
    __syncthreads();
    const float* w; const float* agg;
    if (t < H){ w = W2ap1 + (size_t)t*(2*H2);     agg = a5; }
    else      { w = W2ap2 + (size_t)(t-H)*(2*H2); agg = a6; }
    float s0=0.f,s1=0.f,s2=0.f,s3=0.f;
    for (int c=0;c<H2;c+=4){
      s0 = fmaf(w[c  ], xa[c  ], s0);
      s1 = fmaf(w[c+1], xa[c+1], s1);
      s2 = fmaf(w[c+2], xa[c+2], s2);
      s3 = fmaf(w[c+3], xa[c+3], s3);
    }
    for (int c=0;c<H2;c+=4){
      s0 = fmaf(w[H2+c  ], agg[c  ], s0);
      s1 = fmaf(w[H2+c+1], agg[c+1], s1);
      s2 = fmaf(w[H2+c+2], agg[c+2], s2);
      s3 = fmaf(w[H2+c+3], agg[c+3], s3);
    }
    xs2[t] = frelu((s0+s1)+(s2+s3));
    __syncthreads();
    float hid = bais_ap[i];
    const float* wr1 = wap1 + (size_t)t*H2;
    for (int c=0;c<H2;c++) hid = fmaf(wr1[c], xs2[c], hid);
    red[t] = wap2[t]*hid;
    __syncthreads();
    for (int o=128;o>0;o>>=1){ if (t<o) red[t]+=red[t+o]; __syncthreads(); }
    if (t==0) out_pc[i] = 1.f/(1.f+expf(-red[0]));
  }
}

// ---------------- launch 5: x7/x8 assemble ----------------
__global__ __launch_bounds__(256) void k_x7x8b(
    float* __restrict__ X2ue, const float* __restrict__ P7t,
    const float* __restrict__ Yb8, const int* __restrict__ adj_ue,
    const int* __restrict__ ue2ue)
{
  __shared__ int aj[SS], u2[SS];
  int u = blockIdx.x, t = threadIdx.x;
  if (t < SS){ aj[t] = adj_ue[u*SS+t]; u2[t] = ue2ue[u*SS+t]; }
  __syncthreads();
  float g = X2ue[(size_t)u*H2 + t];
  float s = 0.f;
  if (t < H){
    for (int q=0;q<SS;q++) s += P7t[(size_t)aj[q]*H + t];
  } else {
    for (int q=0;q<SS;q++) s += Yb8[(size_t)u2[q]*H + (t-H)];
  }
  X2ue[(size_t)u*H2 + t] = frelu(g + s*INV_NEIGH);
}

// ---------------- launch 6: BN partial stats ----------------
__global__ __launch_bounds__(256) void k_bn_part(const float* __restrict__ X2ue,
                                                 float* __restrict__ part){
  int b = blockIdx.x, c = threadIdx.x;
  float s=0.f, s2=0.f;
  for (int u = b*50; u < (b+1)*50; u++){
    float v = X2ue[(size_t)u*H2 + c];
    s += v; s2 += v*v;
  }
  part[b*512 + c] = s;
  part[b*512 + 256 + c] = s2;
}

// ---------------- launch 7: UA head, BN scale/shift computed per block ----------------
__global__ __launch_bounds__(128) void k_ua_head3(
    const float* __restrict__ X2ue, const float* __restrict__ part,
    const float* __restrict__ gamma, const float* __restrict__ beta,
    const float* __restrict__ wue, const float* __restrict__ bais_ue,
    float* __restrict__ out)
{
  __shared__ float xs[8][H2];
  __shared__ float scs[H2], shs[H2];
  __shared__ float wmax[2], wmin[2], ws1[2], ws2[2];
  int u0 = blockIdx.x*8, t = threadIdx.x;
  for (int c = t; c < H2; c += 128){
    float s=0.f, s2=0.f;
    for (int b=0;b<BNB;b++){ s += part[b*512+c]; s2 += part[b*512+256+c]; }
    float mean = s*(1.f/UEN);
    float var  = s2*(1.f/UEN) - mean*mean;      // biased, training-mode BN
    float sc = gamma[c]*rsqrtf(var + 1e-5f);
    scs[c] = sc;
    shs[c] = beta[c] - mean*sc;
  }
  __syncthreads();
  #pragma unroll
  for (int q=0;q<8;q++){
    xs[q][t]     = X2ue[(size_t)(u0+q)*H2 + t]*scs[t] + shs[t];
    xs[q][t+128] = X2ue[(size_t)(u0+q)*H2 + t + 128]*scs[t+128] + shs[t+128];
  }
  __syncthreads();
  int a = t;                                    // lanes 0..104 active
  float acc[8];
  #pragma unroll
  for (int q=0;q<8;q++) acc[q] = 0.f;
  if (a < APN){
    #pragma unroll
    for (int q=0;q<8;q++) acc[q] = bais_ue[u0+q];
    const float* wr = wue + (size_t)a*H2;
    for (int c=0;c<H2;c++){
      float w = wr[c];
      #pragma unroll
      for (int q=0;q<8;q++) acc[q] = fmaf(w, xs[q][c], acc[q]);
    }
  }
  int wid = t>>6;
  for (int q=0;q<8;q++){
    float vmax = (a<APN) ? acc[q] : -FLT_MAX;
    float vmin = (a<APN) ? acc[q] :  FLT_MAX;
    #pragma unroll
    for (int o=32;o>0;o>>=1){
      vmax = fmaxf(vmax, __shfl_xor(vmax, o));
      vmin = fminf(vmin, __shfl_xor(vmin, o));
    }
    if ((t&63)==0){ wmax[wid]=vmax; wmin[wid]=vmin; }
    __syncthreads();
    float mx = fmaxf(wmax[0], wmax[1]);
    float mn = fminf(wmin[0], wmin[1]);
    float nor = (a<APN) ? (acc[q]-mx)/(mx-mn) : 0.f;   // in [-1,0]
    float e1 = (a<APN) ? expf(nor*1000.f) : 0.f;
    float e2 = (a<APN) ? expf(nor)        : 0.f;
    float s1 = e1, s2 = e2;
    #pragma unroll
    for (int o=32;o>0;o>>=1){
      s1 += __shfl_xor(s1, o);
      s2 += __shfl_xor(s2, o);
    }
    if ((t&63)==0){ ws1[wid]=s1; ws2[wid]=s2; }
    __syncthreads();
    float S1 = ws1[0]+ws1[1], S2 = ws2[0]+ws2[1];
    if (a < APN){
      size_t u = u0+q;
      out[u*APN + a]                     = acc[q];   // UA_ori
      out[(size_t)UEN*APN   + u*APN + a] = e1/S1;    // UA_de
      out[(size_t)2*UEN*APN + u*APN + a] = e2/S2;    // UA_st
    }
  }
}

extern "C" void kernel_launch(void* const* d_in, const int* in_sizes, int n_in,
                              void* d_out, int out_size, void* d_ws, size_t ws_size,
                              hipStream_t stream) {
  const float* pl      = (const float*)d_in[0];
  const int*   adj_ue  = (const int*)d_in[2];
  const int*   adj_ap  = (const int*)d_in[3];
  const float* W1ap1   = (const float*)d_in[4];
  const float* W1ap2   = (const float*)d_in[5];
  const float* W1ue1   = (const float*)d_in[6];
  const float* W1ue2   = (const float*)d_in[7];
  const float* W2ap1   = (const float*)d_in[8];
  const float* W2ap2   = (const float*)d_in[9];
  const float* W2ue1   = (const float*)d_in[10];
  const float* W2ue2   = (const float*)d_in[11];
  const float* wap1    = (const float*)d_in[12];
  const float* wap2    = (const float*)d_in[13];
  const float* bais_ap = (const float*)d_in[14];
  const float* wue     = (const float*)d_in[15];
  const float* bais_ue = (const float*)d_in[16];
  const float* gamma   = (const float*)d_in[17];
  const float* beta    = (const float*)d_in[18];
  float* out = (float*)d_out;
  (void)in_sizes; (void)n_in; (void)out_size; (void)ws_size;

  char* ws = (char*)d_ws;
  size_t off = 0;
  auto alloc = [&](size_t bytes)->char*{
    char* p = ws + off; off += (bytes + 255) & ~(size_t)255; return p;
  };
  int*   ap2ap  = (int*)alloc(APN*SS*4);
  int*   ue2ue  = (int*)alloc(UEN*SS*4);
  float* Xap    = (float*)alloc((size_t)APN*H2*4);
  float* Xue    = (float*)alloc((size_t)UEN*H2*4);   // phase1: gemA partials
  float* X2ue   = (float*)alloc((size_t)UEN*H2*4);   // phase1: T3|T4
  float* part   = (float*)alloc((size_t)BNB*512*4);
  // ws-buffer aliases (dead-before-write ordering):
  float* partialA = Xue;               // 64*105*128 fl, dead after k_redA
  float* T3 = X2ue;                    // dead after k_mid1
  float* T4 = X2ue + 512000;           // dead after k_mid1
  // d_out scratch map (floats; out_size = 1,260,106; all dead before final writes):
  float* U1  = out;                    // dead after k_mid1
  float* Yb8 = out;                    // aliases U1 (k_mid2 runs after k_mid1)
  float* R4  = out + 520000;           // dead after k_mid1
  float* RA  = out + 1040000;          // 4*105*128 (G1,G2a,Q2,P3)
  float* P3t = RA + (size_t)3*APN*H;
  float* P7t = out + 1100000;
  float* out_pc = out + (size_t)3*UEN*APN;          // [1260000..1260105)
  float* out_sc = out + (size_t)3*UEN*APN + APN;    // [1260105]

  k_front   <<<dim3(NB_FRONT), 256, 0, stream>>>(pl, W1ap1, W1ap2, W1ue1, W1ue2,
                                                 adj_ue, adj_ap, ap2ap, ue2ue,
                                                 partialA, T3, T4, U1, R4,
                                                 wue, out_sc);
  k_redA    <<<dim3((4*APN*H+255)/256), 256, 0, stream>>>(partialA, RA);
  k_mid1    <<<dim3(UEN+APN), 256, 0, stream>>>(T3, T4, P3t, R4, RA, U1,
                                                adj_ue, ue2ue, adj_ap, ap2ap,
                                                Xue, Xap);
  k_mid2    <<<dim3(588), 256, 0, stream>>>(Xue, Xap, W2ue1, W2ue2, W2ap1, W2ap2,
                                            adj_ap, ap2ap, wap1, wap2, bais_ap,
                                            X2ue, Yb8, P7t, out_pc);
  k_x7x8b   <<<dim3(UEN), 256, 0, stream>>>(X2ue, P7t, Yb8, adj_ue, ue2ue);
  k_bn_part <<<dim3(BNB), 256, 0, stream>>>(X2ue, part);
  k_ua_head3<<<dim3(UEN/8), 128, 0, stream>>>(X2ue, part, gamma, beta, wue,
                                              bais_ue, out);
}